// Round 1
// baseline (181.804 us; speedup 1.0000x reference)
//
#include <hip/hip_runtime.h>

typedef unsigned short ushort_t;
typedef __attribute__((ext_vector_type(8))) short bf16x8;
typedef __attribute__((ext_vector_type(4))) float f32x4;

#define BS 2
#define NS 48
#define NO 48
#define RD 512
#define MD 256
#define M1 (BS*NS*NO)   // 4608 rows of p1/p2
#define LN_EPS 1e-6f

__device__ __forceinline__ short f2bf(float f) {
    union { float f; unsigned u; } v; v.f = f;
    unsigned u = v.u;
    return (short)((u + 0x7fffu + ((u >> 16) & 1u)) >> 16);  // RNE
}

// ---------------------------------------------------------------------------
// prep: transpose + cast weights to bf16, layout WT[n][k] (row n, contiguous k)
// ---------------------------------------------------------------------------
__global__ __launch_bounds__(256) void prep_kernel(
    const float* __restrict__ W1, const float* __restrict__ W2,
    const float* __restrict__ We,
    ushort_t* __restrict__ w1t, ushort_t* __restrict__ w2t,
    ushort_t* __restrict__ wet)
{
    int n = blockIdx.x;     // 0..255 (output col of W1/W2/We)
    int t = threadIdx.x;    // 0..255
#pragma unroll
    for (int k = t; k < RD; k += 256) {
        w1t[n * RD + k] = (ushort_t)f2bf(W1[k * MD + n]);
        w2t[n * RD + k] = (ushort_t)f2bf(W2[k * MD + n]);
    }
    wet[n * MD + t] = (ushort_t)f2bf(We[t * MD + n]);
}

// ---------------------------------------------------------------------------
// stage1: P1 = rel @ W1 + b1, P2 = rel @ W2 + b2   (fp32 out, bf16 MFMA)
// grid = 288 blocks (one 16-row m-tile each), 256 threads (4 waves).
// wave 0: P1 cols 0-127, wave 1: P1 cols 128-255, wave 2/3: same for P2.
// ---------------------------------------------------------------------------
__global__ __launch_bounds__(256) void stage1_kernel(
    const float* __restrict__ rel,
    const ushort_t* __restrict__ w1t, const ushort_t* __restrict__ w2t,
    const float* __restrict__ b1, const float* __restrict__ b2,
    float* __restrict__ p1, float* __restrict__ p2)
{
    int mt   = blockIdx.x;          // 0..287
    int tid  = threadIdx.x;
    int wid  = tid >> 6;
    int lane = tid & 63;
    int lr   = lane & 15;           // row-in-tile (A) / col-in-tile (B,D)
    int lg   = lane >> 4;           // k-group

    const ushort_t* wt  = (wid < 2) ? w1t : w2t;
    const float* bias   = (wid < 2) ? b1 : b2;
    float* out          = (wid < 2) ? p1 : p2;
    int n0 = (wid & 1) * 128;

    int arow = mt * 16 + lr;
    const float* ap = rel + (size_t)arow * RD;

    f32x4 acc[8] = {};
#pragma unroll
    for (int ks = 0; ks < 16; ++ks) {
        int k0 = ks * 32 + lg * 8;
        float4 a0 = *reinterpret_cast<const float4*>(ap + k0);
        float4 a1 = *reinterpret_cast<const float4*>(ap + k0 + 4);
        bf16x8 af;
        af[0] = f2bf(a0.x); af[1] = f2bf(a0.y); af[2] = f2bf(a0.z); af[3] = f2bf(a0.w);
        af[4] = f2bf(a1.x); af[5] = f2bf(a1.y); af[6] = f2bf(a1.z); af[7] = f2bf(a1.w);
#pragma unroll
        for (int nt = 0; nt < 8; ++nt) {
            const ushort_t* bp = wt + (size_t)(n0 + nt * 16 + lr) * RD + k0;
            bf16x8 bfr = *reinterpret_cast<const bf16x8*>(bp);
            acc[nt] = __builtin_amdgcn_mfma_f32_16x16x32_bf16(af, bfr, acc[nt], 0, 0, 0);
        }
    }
#pragma unroll
    for (int nt = 0; nt < 8; ++nt) {
        int col = n0 + nt * 16 + lr;
        float bv = bias[col];
#pragma unroll
        for (int r = 0; r < 4; ++r) {
            int orow = mt * 16 + lg * 4 + r;
            out[(size_t)orow * MD + col] = acc[nt][r] + bv;
        }
    }
}

// ---------------------------------------------------------------------------
// stage2: one block per (b,s,o1). rows = 48 o2-values.
//   prod[o2][m] = P1[bid][m] * P2[group+o2][m]  -> bf16 LDS (XOR swizzled)
//   h = prod @ We + be, then LayerNorm, store fp32.
// 256 threads = 4 waves; wave w covers cols [w*64, w*64+64).
// ---------------------------------------------------------------------------
__global__ __launch_bounds__(256) void stage2_kernel(
    const float* __restrict__ p1, const float* __restrict__ p2,
    const ushort_t* __restrict__ wet,
    const float* __restrict__ be, const float* __restrict__ gamma,
    const float* __restrict__ beta, float* __restrict__ out)
{
    __shared__ __align__(16) char ldsA[NO * MD * 2];   // 48 rows * 256 bf16 = 24576 B
    __shared__ float pS1[4][NO];
    __shared__ float pS2[4][NO];

    int bid  = blockIdx.x;            // 0..4607 == p1 row (b,s,o1)
    int grp  = (bid / NO) * NO;       // first p2 row of this (b,s)
    int tid  = threadIdx.x;
    int wid  = tid >> 6;
    int lane = tid & 63;
    int lr   = lane & 15;
    int lg   = lane >> 4;

    // ---- stage prod into LDS (swizzled) ----
    const float* p1r = p1 + (size_t)bid * MD;
#pragma unroll
    for (int i = 0; i < 6; ++i) {
        int c  = i * 256 + tid;       // 0..1535 chunks of 8 elements
        int r  = c >> 5;              // row 0..47
        int m0 = (c & 31) * 8;        // col 0..248
        float4 x0 = *reinterpret_cast<const float4*>(p1r + m0);
        float4 x1 = *reinterpret_cast<const float4*>(p1r + m0 + 4);
        const float* p2r = p2 + (size_t)(grp + r) * MD;
        float4 y0 = *reinterpret_cast<const float4*>(p2r + m0);
        float4 y1 = *reinterpret_cast<const float4*>(p2r + m0 + 4);
        bf16x8 v;
        v[0] = f2bf(x0.x * y0.x); v[1] = f2bf(x0.y * y0.y);
        v[2] = f2bf(x0.z * y0.z); v[3] = f2bf(x0.w * y0.w);
        v[4] = f2bf(x1.x * y1.x); v[5] = f2bf(x1.y * y1.y);
        v[6] = f2bf(x1.z * y1.z); v[7] = f2bf(x1.w * y1.w);
        int byteoff = (m0 * 2) ^ ((r & 7) << 4);
        *reinterpret_cast<bf16x8*>(ldsA + r * (MD * 2) + byteoff) = v;
    }
    __syncthreads();

    // ---- K-loop: 8 steps of 32 ----
    int n0 = wid * 64;
    f32x4 acc[3][4] = {};
#pragma unroll
    for (int ks = 0; ks < 8; ++ks) {
        int kb = ks * 64 + lg * 16;   // byte offset of this lane's k-slice
        bf16x8 a[3];
#pragma unroll
        for (int mtl = 0; mtl < 3; ++mtl) {
            int r = mtl * 16 + lr;
            a[mtl] = *reinterpret_cast<const bf16x8*>(
                ldsA + r * (MD * 2) + (kb ^ ((r & 7) << 4)));
        }
#pragma unroll
        for (int nt = 0; nt < 4; ++nt) {
            const ushort_t* bp = wet + (size_t)(n0 + nt * 16 + lr) * MD + (ks * 32 + lg * 8);
            bf16x8 b = *reinterpret_cast<const bf16x8*>(bp);
#pragma unroll
            for (int mtl = 0; mtl < 3; ++mtl)
                acc[mtl][nt] = __builtin_amdgcn_mfma_f32_16x16x32_bf16(a[mtl], b, acc[mtl][nt], 0, 0, 0);
        }
    }

    // ---- add be, per-wave partial sums for LN ----
#pragma unroll
    for (int nt = 0; nt < 4; ++nt) {
        float bev = be[n0 + nt * 16 + lr];
#pragma unroll
        for (int mtl = 0; mtl < 3; ++mtl)
#pragma unroll
            for (int r = 0; r < 4; ++r)
                acc[mtl][nt][r] += bev;
    }

#pragma unroll
    for (int mtl = 0; mtl < 3; ++mtl) {
#pragma unroll
        for (int r = 0; r < 4; ++r) {
            float s1 = 0.f, s2 = 0.f;
#pragma unroll
            for (int nt = 0; nt < 4; ++nt) {
                float v = acc[mtl][nt][r];
                s1 += v; s2 += v * v;
            }
#pragma unroll
            for (int m = 1; m < 16; m <<= 1) {
                s1 += __shfl_xor(s1, m);
                s2 += __shfl_xor(s2, m);
            }
            if (lr == 0) {
                int row = mtl * 16 + lg * 4 + r;
                pS1[wid][row] = s1;
                pS2[wid][row] = s2;
            }
        }
    }
    __syncthreads();

    // ---- final stats + store ----
    float mu[3][4], rs[3][4];
#pragma unroll
    for (int mtl = 0; mtl < 3; ++mtl) {
#pragma unroll
        for (int r = 0; r < 4; ++r) {
            int row = mtl * 16 + lg * 4 + r;
            float S1 = pS1[0][row] + pS1[1][row] + pS1[2][row] + pS1[3][row];
            float S2 = pS2[0][row] + pS2[1][row] + pS2[2][row] + pS2[3][row];
            float m  = S1 * (1.0f / MD);
            float var = S2 * (1.0f / MD) - m * m;
            mu[mtl][r] = m;
            rs[mtl][r] = rsqrtf(var + LN_EPS);
        }
    }

    size_t ob = (size_t)bid * NO * MD;
#pragma unroll
    for (int nt = 0; nt < 4; ++nt) {
        int col = n0 + nt * 16 + lr;
        float g  = gamma[col];
        float bt = beta[col];
#pragma unroll
        for (int mtl = 0; mtl < 3; ++mtl) {
#pragma unroll
            for (int r = 0; r < 4; ++r) {
                int row = mtl * 16 + lg * 4 + r;
                out[ob + (size_t)row * MD + col] =
                    (acc[mtl][nt][r] - mu[mtl][r]) * rs[mtl][r] * g + bt;
            }
        }
    }
}

// ---------------------------------------------------------------------------
extern "C" void kernel_launch(void* const* d_in, const int* in_sizes, int n_in,
                              void* d_out, int out_size, void* d_ws, size_t ws_size,
                              hipStream_t stream) {
    const float* rel   = (const float*)d_in[0];
    const float* W1    = (const float*)d_in[1];
    const float* b1    = (const float*)d_in[2];
    const float* W2    = (const float*)d_in[3];
    const float* b2    = (const float*)d_in[4];
    const float* We    = (const float*)d_in[5];
    const float* be    = (const float*)d_in[6];
    const float* gamma = (const float*)d_in[7];
    const float* beta  = (const float*)d_in[8];
    float* out = (float*)d_out;

    char* ws = (char*)d_ws;
    // ws layout (bytes): w1t 256K | w2t 256K | wet 128K | p1 4.5M | p2 4.5M
    ushort_t* w1t = (ushort_t*)(ws);
    ushort_t* w2t = (ushort_t*)(ws + 262144);
    ushort_t* wet = (ushort_t*)(ws + 524288);
    float*    p1  = (float*)   (ws + 655360);
    float*    p2  = (float*)   (ws + 655360 + 4718592);

    prep_kernel<<<256, 256, 0, stream>>>(W1, W2, We, w1t, w2t, wet);
    stage1_kernel<<<288, 256, 0, stream>>>(rel, w1t, w2t, b1, b2, p1, p2);
    stage2_kernel<<<M1, 256, 0, stream>>>(p1, p2, wet, be, gamma, beta, out);
}

// Round 2
// 138.842 us; speedup vs baseline: 1.3094x; 1.3094x over previous
//
#include <hip/hip_runtime.h>

typedef unsigned short ushort_t;
typedef __attribute__((ext_vector_type(8))) short bf16x8;
typedef __attribute__((ext_vector_type(4))) float f32x4;

#define BS 2
#define NS 48
#define NO 48
#define RD 512
#define MD 256
#define M1 (BS*NS*NO)   // 4608 rows of p1/p2
#define LN_EPS 1e-6f

__device__ __forceinline__ short f2bf(float f) {
    union { float f; unsigned u; } v; v.f = f;
    unsigned u = v.u;
    return (short)((u + 0x7fffu + ((u >> 16) & 1u)) >> 16);  // RNE
}

// ---------------------------------------------------------------------------
// prep: tiled transpose + cast to bf16.  dst[n][k] = src[k][n].
// 80 blocks: 0-31 -> W1 (512x256), 32-63 -> W2, 64-79 -> We (256x256).
// 256 threads as (tx=64, ty=4); 64x64 fp32 LDS tile, +1 pad col.
// ---------------------------------------------------------------------------
__global__ __launch_bounds__(256) void prep_kernel(
    const float* __restrict__ W1, const float* __restrict__ W2,
    const float* __restrict__ We,
    ushort_t* __restrict__ w1t, ushort_t* __restrict__ w2t,
    ushort_t* __restrict__ wet)
{
    __shared__ float tile[64][65];
    int b = blockIdx.x;
    const float* src; ushort_t* dst; int Mk, tR, tC;
    if (b < 32)       { src = W1; dst = w1t; Mk = 512; tR = b >> 2;        tC = b & 3; }
    else if (b < 64)  { src = W2; dst = w2t; Mk = 512; tR = (b - 32) >> 2; tC = b & 3; }
    else              { src = We; dst = wet; Mk = 256; tR = (b - 64) >> 2; tC = b & 3; }
    int tx = threadIdx.x & 63;
    int ty = threadIdx.x >> 6;
    int R0 = tR * 64, C0 = tC * 64;
#pragma unroll
    for (int rr = 0; rr < 16; ++rr) {
        int k = R0 + ty * 16 + rr;
        tile[ty * 16 + rr][tx] = src[(size_t)k * MD + C0 + tx];
    }
    __syncthreads();
#pragma unroll
    for (int rr = 0; rr < 16; ++rr) {
        int n = C0 + ty * 16 + rr;
        dst[(size_t)n * Mk + R0 + tx] = (ushort_t)f2bf(tile[tx][ty * 16 + rr]);
    }
}

// ---------------------------------------------------------------------------
// stage1: P1 = rel @ W1 + b1, P2 = rel @ W2 + b2   (fp32 out, bf16 MFMA)
// grid = 576 blocks (mt = b>>1, which = b&1), 128 threads (2 waves).
// wave w covers cols [w*128, w*128+128) of P{1|2}.
// ---------------------------------------------------------------------------
__global__ __launch_bounds__(128) void stage1_kernel(
    const float* __restrict__ rel,
    const ushort_t* __restrict__ w1t, const ushort_t* __restrict__ w2t,
    const float* __restrict__ b1, const float* __restrict__ b2,
    float* __restrict__ p1, float* __restrict__ p2)
{
    int blk   = blockIdx.x;
    int mt    = blk >> 1;
    int which = blk & 1;
    int tid   = threadIdx.x;
    int wid   = tid >> 6;
    int lane  = tid & 63;
    int lr    = lane & 15;
    int lg    = lane >> 4;

    const ushort_t* wt  = which ? w2t : w1t;
    const float* bias   = which ? b2 : b1;
    float* out          = which ? p2 : p1;
    int n0 = wid * 128;

    int arow = mt * 16 + lr;
    const float* ap = rel + (size_t)arow * RD;

    f32x4 acc[8] = {};
#pragma unroll
    for (int ks = 0; ks < 16; ++ks) {
        int k0 = ks * 32 + lg * 8;
        float4 a0 = *reinterpret_cast<const float4*>(ap + k0);
        float4 a1 = *reinterpret_cast<const float4*>(ap + k0 + 4);
        bf16x8 af;
        af[0] = f2bf(a0.x); af[1] = f2bf(a0.y); af[2] = f2bf(a0.z); af[3] = f2bf(a0.w);
        af[4] = f2bf(a1.x); af[5] = f2bf(a1.y); af[6] = f2bf(a1.z); af[7] = f2bf(a1.w);
#pragma unroll
        for (int nt = 0; nt < 8; ++nt) {
            const ushort_t* bp = wt + (size_t)(n0 + nt * 16 + lr) * RD + k0;
            bf16x8 bfr = *reinterpret_cast<const bf16x8*>(bp);
            acc[nt] = __builtin_amdgcn_mfma_f32_16x16x32_bf16(af, bfr, acc[nt], 0, 0, 0);
        }
    }
#pragma unroll
    for (int nt = 0; nt < 8; ++nt) {
        int col = n0 + nt * 16 + lr;
        float bv = bias[col];
#pragma unroll
        for (int r = 0; r < 4; ++r) {
            int orow = mt * 16 + lg * 4 + r;
            out[(size_t)orow * MD + col] = acc[nt][r] + bv;
        }
    }
}

// ---------------------------------------------------------------------------
// stage2: one block per (b,s,o1); 512 threads = 8 waves; wave owns 32 cols.
// B-operand (wet) fragments hoisted to registers BEFORE the staging barrier,
// so the K-loop is pure LDS + MFMA.
// ---------------------------------------------------------------------------
__global__ __launch_bounds__(512, 4) void stage2_kernel(
    const float* __restrict__ p1, const float* __restrict__ p2,
    const ushort_t* __restrict__ wet,
    const float* __restrict__ be, const float* __restrict__ gamma,
    const float* __restrict__ beta, float* __restrict__ out)
{
    __shared__ __align__(16) char ldsA[NO * MD * 2];   // 48 rows * 512 B = 24576
    __shared__ float pS1[NO][8];
    __shared__ float pS2[NO][8];
    __shared__ float muS[NO];
    __shared__ float rsS[NO];

    int bid  = blockIdx.x;            // p1 row (b,s,o1)
    int grp  = (bid / NO) * NO;       // first p2 row of this (b,s)
    int tid  = threadIdx.x;
    int wid  = tid >> 6;              // 0..7
    int lane = tid & 63;
    int lr   = lane & 15;
    int lg   = lane >> 4;
    int n0   = wid * 32;

    // ---- issue B-fragment loads (registers); overlap with staging below ----
    bf16x8 bfrag[2][8];
#pragma unroll
    for (int nt = 0; nt < 2; ++nt)
#pragma unroll
        for (int ks = 0; ks < 8; ++ks)
            bfrag[nt][ks] = *reinterpret_cast<const bf16x8*>(
                wet + (size_t)(n0 + nt * 16 + lr) * MD + ks * 32 + lg * 8);

    // ---- stage prod into LDS (swizzled): 1536 chunks, 3 per thread ----
    const float* p1r = p1 + (size_t)bid * MD;
#pragma unroll
    for (int i = 0; i < 3; ++i) {
        int c  = i * 512 + tid;       // 0..1535
        int r  = c >> 5;              // row 0..47
        int m0 = (c & 31) * 8;        // col 0..248
        float4 x0 = *reinterpret_cast<const float4*>(p1r + m0);
        float4 x1 = *reinterpret_cast<const float4*>(p1r + m0 + 4);
        const float* p2r = p2 + (size_t)(grp + r) * MD;
        float4 y0 = *reinterpret_cast<const float4*>(p2r + m0);
        float4 y1 = *reinterpret_cast<const float4*>(p2r + m0 + 4);
        bf16x8 v;
        v[0] = f2bf(x0.x * y0.x); v[1] = f2bf(x0.y * y0.y);
        v[2] = f2bf(x0.z * y0.z); v[3] = f2bf(x0.w * y0.w);
        v[4] = f2bf(x1.x * y1.x); v[5] = f2bf(x1.y * y1.y);
        v[6] = f2bf(x1.z * y1.z); v[7] = f2bf(x1.w * y1.w);
        int byteoff = (m0 * 2) ^ ((r & 7) << 4);
        *reinterpret_cast<bf16x8*>(ldsA + r * (MD * 2) + byteoff) = v;
    }
    __syncthreads();

    // ---- K-loop: pure LDS + MFMA (B in registers) ----
    f32x4 acc[3][2] = {};
#pragma unroll
    for (int ks = 0; ks < 8; ++ks) {
        int kb = ks * 64 + lg * 16;
        bf16x8 a[3];
#pragma unroll
        for (int mtl = 0; mtl < 3; ++mtl) {
            int r = mtl * 16 + lr;
            a[mtl] = *reinterpret_cast<const bf16x8*>(
                ldsA + r * (MD * 2) + (kb ^ ((r & 7) << 4)));
        }
#pragma unroll
        for (int nt = 0; nt < 2; ++nt)
#pragma unroll
            for (int mtl = 0; mtl < 3; ++mtl)
                acc[mtl][nt] = __builtin_amdgcn_mfma_f32_16x16x32_bf16(
                    a[mtl], bfrag[nt][ks], acc[mtl][nt], 0, 0, 0);
    }

    // ---- add be, per-wave partial sums for LN ----
#pragma unroll
    for (int nt = 0; nt < 2; ++nt) {
        float bev = be[n0 + nt * 16 + lr];
#pragma unroll
        for (int mtl = 0; mtl < 3; ++mtl)
#pragma unroll
            for (int r = 0; r < 4; ++r)
                acc[mtl][nt][r] += bev;
    }

#pragma unroll
    for (int mtl = 0; mtl < 3; ++mtl) {
#pragma unroll
        for (int r = 0; r < 4; ++r) {
            float s1 = 0.f, s2 = 0.f;
#pragma unroll
            for (int nt = 0; nt < 2; ++nt) {
                float v = acc[mtl][nt][r];
                s1 += v; s2 += v * v;
            }
#pragma unroll
            for (int m = 1; m < 16; m <<= 1) {
                s1 += __shfl_xor(s1, m);
                s2 += __shfl_xor(s2, m);
            }
            if (lr == 0) {
                int row = mtl * 16 + lg * 4 + r;
                pS1[row][wid] = s1;
                pS2[row][wid] = s2;
            }
        }
    }
    __syncthreads();

    // ---- finalize stats: one thread per row ----
    if (tid < NO) {
        f32x4 a0 = *reinterpret_cast<const f32x4*>(&pS1[tid][0]);
        f32x4 a1 = *reinterpret_cast<const f32x4*>(&pS1[tid][4]);
        f32x4 b0 = *reinterpret_cast<const f32x4*>(&pS2[tid][0]);
        f32x4 b1v = *reinterpret_cast<const f32x4*>(&pS2[tid][4]);
        float S1 = a0[0]+a0[1]+a0[2]+a0[3] + a1[0]+a1[1]+a1[2]+a1[3];
        float S2 = b0[0]+b0[1]+b0[2]+b0[3] + b1v[0]+b1v[1]+b1v[2]+b1v[3];
        float m  = S1 * (1.0f / MD);
        float var = S2 * (1.0f / MD) - m * m;
        muS[tid] = m;
        rsS[tid] = rsqrtf(var + LN_EPS);
    }
    __syncthreads();

    // ---- store ----
    size_t ob = (size_t)bid * NO * MD;
#pragma unroll
    for (int nt = 0; nt < 2; ++nt) {
        int col = n0 + nt * 16 + lr;
        float g  = gamma[col];
        float bt = beta[col];
#pragma unroll
        for (int mtl = 0; mtl < 3; ++mtl) {
#pragma unroll
            for (int r = 0; r < 4; ++r) {
                int row = mtl * 16 + lg * 4 + r;
                out[ob + (size_t)row * MD + col] =
                    (acc[mtl][nt][r] - muS[row]) * rsS[row] * g + bt;
            }
        }
    }
}

// ---------------------------------------------------------------------------
extern "C" void kernel_launch(void* const* d_in, const int* in_sizes, int n_in,
                              void* d_out, int out_size, void* d_ws, size_t ws_size,
                              hipStream_t stream) {
    const float* rel   = (const float*)d_in[0];
    const float* W1    = (const float*)d_in[1];
    const float* b1    = (const float*)d_in[2];
    const float* W2    = (const float*)d_in[3];
    const float* b2    = (const float*)d_in[4];
    const float* We    = (const float*)d_in[5];
    const float* be    = (const float*)d_in[6];
    const float* gamma = (const float*)d_in[7];
    const float* beta  = (const float*)d_in[8];
    float* out = (float*)d_out;

    char* ws = (char*)d_ws;
    // ws layout (bytes): w1t 256K | w2t 256K | wet 128K | p1 4.5M | p2 4.5M
    ushort_t* w1t = (ushort_t*)(ws);
    ushort_t* w2t = (ushort_t*)(ws + 262144);
    ushort_t* wet = (ushort_t*)(ws + 524288);
    float*    p1  = (float*)   (ws + 655360);
    float*    p2  = (float*)   (ws + 655360 + 4718592);

    prep_kernel<<<80, 256, 0, stream>>>(W1, W2, We, w1t, w2t, wet);
    stage1_kernel<<<576, 128, 0, stream>>>(rel, w1t, w2t, b1, b2, p1, p2);
    stage2_kernel<<<M1, 512, 0, stream>>>(p1, p2, wet, be, gamma, beta, out);
}

// Round 3
// 138.144 us; speedup vs baseline: 1.3160x; 1.0051x over previous
//
#include <hip/hip_runtime.h>

typedef unsigned short ushort_t;
typedef __attribute__((ext_vector_type(8))) short bf16x8;
typedef __attribute__((ext_vector_type(4))) float f32x4;

#define BS 2
#define NS 48
#define NO 48
#define RD 512
#define MD 256
#define M1 (BS*NS*NO)   // 4608 rows of p1/p2
#define LN_EPS 1e-6f

__device__ __forceinline__ short f2bf(float f) {
    union { float f; unsigned u; } v; v.f = f;
    unsigned u = v.u;
    return (short)((u + 0x7fffu + ((u >> 16) & 1u)) >> 16);  // RNE
}

// ---------------------------------------------------------------------------
// prep: tiled transpose + cast to bf16.  dst[n][k] = src[k][n].
// 80 blocks: 0-31 -> W1 (512x256), 32-63 -> W2, 64-79 -> We (256x256).
// ---------------------------------------------------------------------------
__global__ __launch_bounds__(256) void prep_kernel(
    const float* __restrict__ W1, const float* __restrict__ W2,
    const float* __restrict__ We,
    ushort_t* __restrict__ w1t, ushort_t* __restrict__ w2t,
    ushort_t* __restrict__ wet)
{
    __shared__ float tile[64][65];
    int b = blockIdx.x;
    const float* src; ushort_t* dst; int Mk, tR, tC;
    if (b < 32)       { src = W1; dst = w1t; Mk = 512; tR = b >> 2;        tC = b & 3; }
    else if (b < 64)  { src = W2; dst = w2t; Mk = 512; tR = (b - 32) >> 2; tC = b & 3; }
    else              { src = We; dst = wet; Mk = 256; tR = (b - 64) >> 2; tC = b & 3; }
    int tx = threadIdx.x & 63;
    int ty = threadIdx.x >> 6;
    int R0 = tR * 64, C0 = tC * 64;
#pragma unroll
    for (int rr = 0; rr < 16; ++rr) {
        int k = R0 + ty * 16 + rr;
        tile[ty * 16 + rr][tx] = src[(size_t)k * MD + C0 + tx];
    }
    __syncthreads();
#pragma unroll
    for (int rr = 0; rr < 16; ++rr) {
        int n = C0 + ty * 16 + rr;
        dst[(size_t)n * Mk + R0 + tx] = (ushort_t)f2bf(tile[tx][ty * 16 + rr]);
    }
}

// ---------------------------------------------------------------------------
// stage1: P1 = rel @ W1 + b1, P2 = rel @ W2 + b2   (fp32 out, bf16 MFMA)
// grid = 1152 blocks: mt = b>>2 (16-row tile), which = (b>>1)&1, half = b&1.
// 128 threads (2 waves); wave covers 64 cols.
// ---------------------------------------------------------------------------
__global__ __launch_bounds__(128) void stage1_kernel(
    const float* __restrict__ rel,
    const ushort_t* __restrict__ w1t, const ushort_t* __restrict__ w2t,
    const float* __restrict__ b1, const float* __restrict__ b2,
    float* __restrict__ p1, float* __restrict__ p2)
{
    int blk   = blockIdx.x;
    int mt    = blk >> 2;
    int which = (blk >> 1) & 1;
    int half  = blk & 1;
    int tid   = threadIdx.x;
    int wid   = tid >> 6;
    int lane  = tid & 63;
    int lr    = lane & 15;
    int lg    = lane >> 4;

    const ushort_t* wt  = which ? w2t : w1t;
    const float* bias   = which ? b2 : b1;
    float* out          = which ? p2 : p1;
    int n0 = half * 128 + wid * 64;

    int arow = mt * 16 + lr;
    const float* ap = rel + (size_t)arow * RD;

    f32x4 acc[4] = {};
#pragma unroll
    for (int ks = 0; ks < 16; ++ks) {
        int k0 = ks * 32 + lg * 8;
        float4 a0 = *reinterpret_cast<const float4*>(ap + k0);
        float4 a1 = *reinterpret_cast<const float4*>(ap + k0 + 4);
        bf16x8 af;
        af[0] = f2bf(a0.x); af[1] = f2bf(a0.y); af[2] = f2bf(a0.z); af[3] = f2bf(a0.w);
        af[4] = f2bf(a1.x); af[5] = f2bf(a1.y); af[6] = f2bf(a1.z); af[7] = f2bf(a1.w);
#pragma unroll
        for (int nt = 0; nt < 4; ++nt) {
            const ushort_t* bp = wt + (size_t)(n0 + nt * 16 + lr) * RD + k0;
            bf16x8 bfr = *reinterpret_cast<const bf16x8*>(bp);
            acc[nt] = __builtin_amdgcn_mfma_f32_16x16x32_bf16(af, bfr, acc[nt], 0, 0, 0);
        }
    }
#pragma unroll
    for (int nt = 0; nt < 4; ++nt) {
        int col = n0 + nt * 16 + lr;
        float bv = bias[col];
#pragma unroll
        for (int r = 0; r < 4; ++r) {
            int orow = mt * 16 + lg * 4 + r;
            out[(size_t)orow * MD + col] = acc[nt][r] + bv;
        }
    }
}

// ---------------------------------------------------------------------------
// stage2: one block per (b,s,o1); 512 threads = 8 waves; wave owns 32 cols.
// B (wet) fragments hoisted in TWO 4-Kstep batches (32 VGPR each) to stay
// under the 128-VGPR cap (no spills). Batch1 overlaps staging; batch2's L2
// latency is covered by the first half of the K-loop.
// ---------------------------------------------------------------------------
__global__ __launch_bounds__(512, 4) void stage2_kernel(
    const float* __restrict__ p1, const float* __restrict__ p2,
    const ushort_t* __restrict__ wet,
    const float* __restrict__ be, const float* __restrict__ gamma,
    const float* __restrict__ beta, float* __restrict__ out)
{
    __shared__ __align__(16) char ldsA[NO * MD * 2];   // 48 rows * 512 B = 24576
    __shared__ float pS1[NO][8];
    __shared__ float pS2[NO][8];
    __shared__ float muS[NO];
    __shared__ float rsS[NO];

    int bid  = blockIdx.x;            // p1 row (b,s,o1)
    int grp  = (bid / NO) * NO;       // first p2 row of this (b,s)
    int tid  = threadIdx.x;
    int wid  = tid >> 6;              // 0..7
    int lane = tid & 63;
    int lr   = lane & 15;
    int lg   = lane >> 4;
    int n0   = wid * 32;

    const ushort_t* wbase = wet + (size_t)lr * MD + lg * 8;

    // ---- B batch 1 (ks 0..3): issue before staging so loads overlap ----
    bf16x8 bfA[2][4];
#pragma unroll
    for (int nt = 0; nt < 2; ++nt)
#pragma unroll
        for (int ks = 0; ks < 4; ++ks)
            bfA[nt][ks] = *reinterpret_cast<const bf16x8*>(
                wbase + (size_t)(n0 + nt * 16) * MD + ks * 32);

    // ---- stage prod into LDS (swizzled): 1536 chunks, 3 per thread ----
    const float* p1r = p1 + (size_t)bid * MD;
#pragma unroll
    for (int i = 0; i < 3; ++i) {
        int c  = i * 512 + tid;       // 0..1535
        int r  = c >> 5;              // row 0..47
        int m0 = (c & 31) * 8;        // col 0..248
        float4 x0 = *reinterpret_cast<const float4*>(p1r + m0);
        float4 x1 = *reinterpret_cast<const float4*>(p1r + m0 + 4);
        const float* p2r = p2 + (size_t)(grp + r) * MD;
        float4 y0 = *reinterpret_cast<const float4*>(p2r + m0);
        float4 y1 = *reinterpret_cast<const float4*>(p2r + m0 + 4);
        bf16x8 v;
        v[0] = f2bf(x0.x * y0.x); v[1] = f2bf(x0.y * y0.y);
        v[2] = f2bf(x0.z * y0.z); v[3] = f2bf(x0.w * y0.w);
        v[4] = f2bf(x1.x * y1.x); v[5] = f2bf(x1.y * y1.y);
        v[6] = f2bf(x1.z * y1.z); v[7] = f2bf(x1.w * y1.w);
        int byteoff = (m0 * 2) ^ ((r & 7) << 4);
        *reinterpret_cast<bf16x8*>(ldsA + r * (MD * 2) + byteoff) = v;
    }
    __syncthreads();

    // ---- B batch 2 (ks 4..7): latency hidden by first half of K-loop ----
    bf16x8 bfB[2][4];
#pragma unroll
    for (int nt = 0; nt < 2; ++nt)
#pragma unroll
        for (int ks = 0; ks < 4; ++ks)
            bfB[nt][ks] = *reinterpret_cast<const bf16x8*>(
                wbase + (size_t)(n0 + nt * 16) * MD + (ks + 4) * 32);

    // ---- K-loop: pure LDS + MFMA ----
    f32x4 acc[3][2] = {};
#pragma unroll
    for (int ks = 0; ks < 8; ++ks) {
        int kb = ks * 64 + lg * 16;
        bf16x8 a[3];
#pragma unroll
        for (int mtl = 0; mtl < 3; ++mtl) {
            int r = mtl * 16 + lr;
            a[mtl] = *reinterpret_cast<const bf16x8*>(
                ldsA + r * (MD * 2) + (kb ^ ((r & 7) << 4)));
        }
#pragma unroll
        for (int nt = 0; nt < 2; ++nt) {
            bf16x8 b = (ks < 4) ? bfA[nt][ks & 3] : bfB[nt][ks & 3];
#pragma unroll
            for (int mtl = 0; mtl < 3; ++mtl)
                acc[mtl][nt] = __builtin_amdgcn_mfma_f32_16x16x32_bf16(
                    a[mtl], b, acc[mtl][nt], 0, 0, 0);
        }
    }

    // ---- add be, per-wave partial sums for LN ----
#pragma unroll
    for (int nt = 0; nt < 2; ++nt) {
        float bev = be[n0 + nt * 16 + lr];
#pragma unroll
        for (int mtl = 0; mtl < 3; ++mtl)
#pragma unroll
            for (int r = 0; r < 4; ++r)
                acc[mtl][nt][r] += bev;
    }

#pragma unroll
    for (int mtl = 0; mtl < 3; ++mtl) {
#pragma unroll
        for (int r = 0; r < 4; ++r) {
            float s1 = 0.f, s2 = 0.f;
#pragma unroll
            for (int nt = 0; nt < 2; ++nt) {
                float v = acc[mtl][nt][r];
                s1 += v; s2 += v * v;
            }
#pragma unroll
            for (int m = 1; m < 16; m <<= 1) {
                s1 += __shfl_xor(s1, m);
                s2 += __shfl_xor(s2, m);
            }
            if (lr == 0) {
                int row = mtl * 16 + lg * 4 + r;
                pS1[row][wid] = s1;
                pS2[row][wid] = s2;
            }
        }
    }
    __syncthreads();

    // ---- finalize stats: one thread per row ----
    if (tid < NO) {
        f32x4 a0 = *reinterpret_cast<const f32x4*>(&pS1[tid][0]);
        f32x4 a1 = *reinterpret_cast<const f32x4*>(&pS1[tid][4]);
        f32x4 b0 = *reinterpret_cast<const f32x4*>(&pS2[tid][0]);
        f32x4 b1v = *reinterpret_cast<const f32x4*>(&pS2[tid][4]);
        float S1 = a0[0]+a0[1]+a0[2]+a0[3] + a1[0]+a1[1]+a1[2]+a1[3];
        float S2 = b0[0]+b0[1]+b0[2]+b0[3] + b1v[0]+b1v[1]+b1v[2]+b1v[3];
        float m  = S1 * (1.0f / MD);
        float var = S2 * (1.0f / MD) - m * m;
        muS[tid] = m;
        rsS[tid] = rsqrtf(var + LN_EPS);
    }
    __syncthreads();

    // ---- store ----
    size_t ob = (size_t)bid * NO * MD;
#pragma unroll
    for (int nt = 0; nt < 2; ++nt) {
        int col = n0 + nt * 16 + lr;
        float g  = gamma[col];
        float bt = beta[col];
#pragma unroll
        for (int mtl = 0; mtl < 3; ++mtl) {
#pragma unroll
            for (int r = 0; r < 4; ++r) {
                int row = mtl * 16 + lg * 4 + r;
                out[ob + (size_t)row * MD + col] =
                    (acc[mtl][nt][r] - muS[row]) * rsS[row] * g + bt;
            }
        }
    }
}

// ---------------------------------------------------------------------------
extern "C" void kernel_launch(void* const* d_in, const int* in_sizes, int n_in,
                              void* d_out, int out_size, void* d_ws, size_t ws_size,
                              hipStream_t stream) {
    const float* rel   = (const float*)d_in[0];
    const float* W1    = (const float*)d_in[1];
    const float* b1    = (const float*)d_in[2];
    const float* W2    = (const float*)d_in[3];
    const float* b2    = (const float*)d_in[4];
    const float* We    = (const float*)d_in[5];
    const float* be    = (const float*)d_in[6];
    const float* gamma = (const float*)d_in[7];
    const float* beta  = (const float*)d_in[8];
    float* out = (float*)d_out;

    char* ws = (char*)d_ws;
    // ws layout (bytes): w1t 256K | w2t 256K | wet 128K | p1 4.5M | p2 4.5M
    ushort_t* w1t = (ushort_t*)(ws);
    ushort_t* w2t = (ushort_t*)(ws + 262144);
    ushort_t* wet = (ushort_t*)(ws + 524288);
    float*    p1  = (float*)   (ws + 655360);
    float*    p2  = (float*)   (ws + 655360 + 4718592);

    prep_kernel<<<80, 256, 0, stream>>>(W1, W2, We, w1t, w2t, wet);
    stage1_kernel<<<1152, 128, 0, stream>>>(rel, w1t, w2t, b1, b2, p1, p2);
    stage2_kernel<<<M1, 512, 0, stream>>>(p1, p2, wet, be, gamma, beta, out);
}

// Round 4
// 105.763 us; speedup vs baseline: 1.7190x; 1.3062x over previous
//
#include <hip/hip_runtime.h>

typedef unsigned short ushort_t;
typedef __attribute__((ext_vector_type(8))) short bf16x8;
typedef __attribute__((ext_vector_type(4))) float f32x4;

#define BS 2
#define NS 48
#define NO 48
#define RD 512
#define MD 256
#define M1 (BS*NS*NO)   // 4608 rows of p1/p2
#define LN_EPS 1e-6f

__device__ __forceinline__ short f2bf(float f) {
    union { float f; unsigned u; } v; v.f = f;
    unsigned u = v.u;
    return (short)((u + 0x7fffu + ((u >> 16) & 1u)) >> 16);  // RNE
}

// ---------------------------------------------------------------------------
// prep: pack W (K x N, f32 row-major) into MFMA B-fragment layout, bf16:
//   dst[((ntG*NKS + ksG)*64 + lane)*8 + e] = W[ksG*32 + (lane>>4)*8 + e][ntG*16 + (lane&15)]
// One block per 64(k) x 64(n) tile, 512 threads.
// Blocks: 0-31 W1 (8kT x 4nT), 32-63 W2, 64-79 We (4kT x 4nT).
// ---------------------------------------------------------------------------
__global__ __launch_bounds__(512) void prep_kernel(
    const float* __restrict__ W1, const float* __restrict__ W2,
    const float* __restrict__ We,
    ushort_t* __restrict__ w1F, ushort_t* __restrict__ w2F,
    ushort_t* __restrict__ weF)
{
    __shared__ float tile[64][65];
    int b = blockIdx.x;
    const float* src; ushort_t* dst; int NKS, kT, nT;
    if (b < 32)      { src = W1; dst = w1F; NKS = 16; kT = b >> 2;        nT = b & 3; }
    else if (b < 64) { src = W2; dst = w2F; NKS = 16; kT = (b - 32) >> 2; nT = b & 3; }
    else             { src = We; dst = weF; NKS = 8;  kT = (b - 64) >> 2; nT = b & 3; }
    int R0 = kT * 64, C0 = nT * 64;
    int tid = threadIdx.x;
#pragma unroll
    for (int pass = 0; pass < 2; ++pass) {
        int kl = pass * 32 + (tid >> 4);
        int nl = (tid & 15) * 4;
        float4 v = *reinterpret_cast<const float4*>(src + (size_t)(R0 + kl) * MD + C0 + nl);
        tile[kl][nl + 0] = v.x; tile[kl][nl + 1] = v.y;
        tile[kl][nl + 2] = v.z; tile[kl][nl + 3] = v.w;
    }
    __syncthreads();
    int f = tid >> 6, lane = tid & 63, lr = lane & 15, lg = lane >> 4;
    int ntl = f >> 1, ksl = f & 1;
    int ntG = (C0 >> 4) + ntl, ksG = (R0 >> 5) + ksl;
    bf16x8 v;
#pragma unroll
    for (int e = 0; e < 8; ++e)
        v[e] = f2bf(tile[ksl * 32 + lg * 8 + e][ntl * 16 + lr]);
    *reinterpret_cast<bf16x8*>(dst + ((size_t)(ntG * NKS + ksG) * 64 + lane) * 8) = v;
}

// ---------------------------------------------------------------------------
// stage1: P1 = rel @ W1 + b1, P2 = rel @ W2 + b2  (bf16 MFMA, fp32 out)
// 576 blocks: mt = b>>1 (16-row tile), which = b&1. 256 threads = 4 waves,
// wave covers 64 cols. A staged coalesced through LDS (swizzled); B from
// fragment-packed w1F/w2F (fully coalesced 1KB loads).
// ---------------------------------------------------------------------------
__global__ __launch_bounds__(256) void stage1_kernel(
    const float* __restrict__ rel,
    const ushort_t* __restrict__ w1F, const ushort_t* __restrict__ w2F,
    const float* __restrict__ b1, const float* __restrict__ b2,
    float* __restrict__ p1, float* __restrict__ p2)
{
    __shared__ __align__(16) char ldsA[16 * RD * 2];   // 16 rows x 512 bf16 = 16 KB
    int blk = blockIdx.x;
    int mt = blk >> 1, which = blk & 1;
    const ushort_t* wF = which ? w2F : w1F;
    const float* bias  = which ? b2 : b1;
    float* out         = which ? p2 : p1;
    int tid = threadIdx.x, wid = tid >> 6, lane = tid & 63;
    int lr = lane & 15, lg = lane >> 4;

    // stage A tile (coalesced row loads, swizzled 8B LDS writes)
#pragma unroll
    for (int it = 0; it < 8; ++it) {
        int rr = it * 2 + (tid >> 7);      // 0..15, uniform per wave
        int c  = (tid & 127) * 4;          // 0..508
        float4 v = *reinterpret_cast<const float4*>(rel + (size_t)(mt * 16 + rr) * RD + c);
        short4 s;
        s.x = f2bf(v.x); s.y = f2bf(v.y); s.z = f2bf(v.z); s.w = f2bf(v.w);
        *reinterpret_cast<short4*>(ldsA + rr * (RD * 2) + ((c * 2) ^ ((rr & 7) << 4))) = s;
    }
    __syncthreads();

    int n0 = wid * 64;
    f32x4 acc[4] = {};
#pragma unroll
    for (int ks = 0; ks < 16; ++ks) {
        bf16x8 a = *reinterpret_cast<const bf16x8*>(
            ldsA + lr * (RD * 2) + ((ks * 64 + lg * 16) ^ ((lr & 7) << 4)));
#pragma unroll
        for (int nt = 0; nt < 4; ++nt) {
            int ntG = (n0 >> 4) + nt;
            bf16x8 bfr = *reinterpret_cast<const bf16x8*>(
                wF + ((size_t)(ntG * 16 + ks) * 64 + lane) * 8);
            acc[nt] = __builtin_amdgcn_mfma_f32_16x16x32_bf16(a, bfr, acc[nt], 0, 0, 0);
        }
    }
#pragma unroll
    for (int nt = 0; nt < 4; ++nt) {
        int col = n0 + nt * 16 + lr;
        float bv = bias[col];
#pragma unroll
        for (int r = 0; r < 4; ++r) {
            int orow = mt * 16 + lg * 4 + r;
            out[(size_t)orow * MD + col] = acc[nt][r] + bv;
        }
    }
}

// ---------------------------------------------------------------------------
// stage2: one block per (b,s,o1); 512 threads = 8 waves; wave owns 32 cols.
// B frags from weF: fully coalesced. Staging: wave builds one full prod row
// per iter (contiguous 1KB p1/p2 reads), swizzled conflict-free LDS writes.
// ---------------------------------------------------------------------------
__global__ __launch_bounds__(512, 4) void stage2_kernel(
    const float* __restrict__ p1, const float* __restrict__ p2,
    const ushort_t* __restrict__ weF,
    const float* __restrict__ be, const float* __restrict__ gamma,
    const float* __restrict__ beta, float* __restrict__ out)
{
    __shared__ __align__(16) char ldsA[NO * MD * 2];   // 24576 B
    __shared__ float pS1[NO][8];
    __shared__ float pS2[NO][8];
    __shared__ float muS[NO];
    __shared__ float rsS[NO];

    int bid  = blockIdx.x;
    int grp  = (bid / NO) * NO;
    int tid  = threadIdx.x;
    int wid  = tid >> 6;
    int lane = tid & 63;
    int lr   = lane & 15;
    int lg   = lane >> 4;
    int n0   = wid * 32;

    // B fragments: 16 fully-coalesced 1KB loads per wave
    bf16x8 bfrag[2][8];
#pragma unroll
    for (int nt = 0; nt < 2; ++nt) {
        int ntG = (n0 >> 4) + nt;
#pragma unroll
        for (int ks = 0; ks < 8; ++ks)
            bfrag[nt][ks] = *reinterpret_cast<const bf16x8*>(
                weF + ((size_t)(ntG * 8 + ks) * 64 + lane) * 8);
    }

    // staging: wave w stages row i*8+w each iter; contiguous 1KB reads
    const float* p1r = p1 + (size_t)bid * MD;
#pragma unroll
    for (int i = 0; i < 6; ++i) {
        int r  = i * 8 + wid;
        int m0 = lane * 4;
        float4 x = *reinterpret_cast<const float4*>(p1r + m0);
        float4 y = *reinterpret_cast<const float4*>(p2 + (size_t)(grp + r) * MD + m0);
        short4 s;
        s.x = f2bf(x.x * y.x); s.y = f2bf(x.y * y.y);
        s.z = f2bf(x.z * y.z); s.w = f2bf(x.w * y.w);
        *reinterpret_cast<short4*>(ldsA + r * (MD * 2) + ((m0 * 2) ^ ((r & 7) << 4))) = s;
    }
    __syncthreads();

    // K-loop: pure LDS + MFMA (B in registers)
    f32x4 acc[3][2] = {};
#pragma unroll
    for (int ks = 0; ks < 8; ++ks) {
        bf16x8 a[3];
#pragma unroll
        for (int mtl = 0; mtl < 3; ++mtl) {
            int r = mtl * 16 + lr;
            a[mtl] = *reinterpret_cast<const bf16x8*>(
                ldsA + r * (MD * 2) + ((ks * 64 + lg * 16) ^ ((r & 7) << 4)));
        }
#pragma unroll
        for (int nt = 0; nt < 2; ++nt)
#pragma unroll
            for (int mtl = 0; mtl < 3; ++mtl)
                acc[mtl][nt] = __builtin_amdgcn_mfma_f32_16x16x32_bf16(
                    a[mtl], bfrag[nt][ks], acc[mtl][nt], 0, 0, 0);
    }

    // add be, per-wave partial sums for LN
#pragma unroll
    for (int nt = 0; nt < 2; ++nt) {
        float bev = be[n0 + nt * 16 + lr];
#pragma unroll
        for (int mtl = 0; mtl < 3; ++mtl)
#pragma unroll
            for (int r = 0; r < 4; ++r)
                acc[mtl][nt][r] += bev;
    }

#pragma unroll
    for (int mtl = 0; mtl < 3; ++mtl) {
#pragma unroll
        for (int r = 0; r < 4; ++r) {
            float s1 = 0.f, s2 = 0.f;
#pragma unroll
            for (int nt = 0; nt < 2; ++nt) {
                float v = acc[mtl][nt][r];
                s1 += v; s2 += v * v;
            }
#pragma unroll
            for (int m = 1; m < 16; m <<= 1) {
                s1 += __shfl_xor(s1, m);
                s2 += __shfl_xor(s2, m);
            }
            if (lr == 0) {
                int row = mtl * 16 + lg * 4 + r;
                pS1[row][wid] = s1;
                pS2[row][wid] = s2;
            }
        }
    }
    __syncthreads();

    if (tid < NO) {
        f32x4 a0 = *reinterpret_cast<const f32x4*>(&pS1[tid][0]);
        f32x4 a1 = *reinterpret_cast<const f32x4*>(&pS1[tid][4]);
        f32x4 b0 = *reinterpret_cast<const f32x4*>(&pS2[tid][0]);
        f32x4 b1v = *reinterpret_cast<const f32x4*>(&pS2[tid][4]);
        float S1 = a0[0]+a0[1]+a0[2]+a0[3] + a1[0]+a1[1]+a1[2]+a1[3];
        float S2 = b0[0]+b0[1]+b0[2]+b0[3] + b1v[0]+b1v[1]+b1v[2]+b1v[3];
        float m  = S1 * (1.0f / MD);
        float var = S2 * (1.0f / MD) - m * m;
        muS[tid] = m;
        rsS[tid] = rsqrtf(var + LN_EPS);
    }
    __syncthreads();

    size_t ob = (size_t)bid * NO * MD;
#pragma unroll
    for (int nt = 0; nt < 2; ++nt) {
        int col = n0 + nt * 16 + lr;
        float g  = gamma[col];
        float bt = beta[col];
#pragma unroll
        for (int mtl = 0; mtl < 3; ++mtl) {
#pragma unroll
            for (int r = 0; r < 4; ++r) {
                int row = mtl * 16 + lg * 4 + r;
                out[ob + (size_t)row * MD + col] =
                    (acc[mtl][nt][r] - muS[row]) * rsS[row] * g + bt;
            }
        }
    }
}

// ---------------------------------------------------------------------------
extern "C" void kernel_launch(void* const* d_in, const int* in_sizes, int n_in,
                              void* d_out, int out_size, void* d_ws, size_t ws_size,
                              hipStream_t stream) {
    const float* rel   = (const float*)d_in[0];
    const float* W1    = (const float*)d_in[1];
    const float* b1    = (const float*)d_in[2];
    const float* W2    = (const float*)d_in[3];
    const float* b2    = (const float*)d_in[4];
    const float* We    = (const float*)d_in[5];
    const float* be    = (const float*)d_in[6];
    const float* gamma = (const float*)d_in[7];
    const float* beta  = (const float*)d_in[8];
    float* out = (float*)d_out;

    char* ws = (char*)d_ws;
    // ws layout (bytes): w1F 512K | w2F 512K | weF 128K | p1 4.5M | p2 4.5M
    ushort_t* w1F = (ushort_t*)(ws);
    ushort_t* w2F = (ushort_t*)(ws + 524288);
    ushort_t* weF = (ushort_t*)(ws + 1048576);
    float*    p1  = (float*)   (ws + 1179648);
    float*    p2  = (float*)   (ws + 1179648 + 4718592);

    prep_kernel<<<80, 512, 0, stream>>>(W1, W2, We, w1F, w2F, weF);
    stage1_kernel<<<576, 256, 0, stream>>>(rel, w1F, w2F, b1, b2, p1, p2);
    stage2_kernel<<<M1, 512, 0, stream>>>(p1, p2, weF, be, gamma, beta, out);
}

// Round 5
// 100.066 us; speedup vs baseline: 1.8168x; 1.0569x over previous
//
#include <hip/hip_runtime.h>

typedef unsigned short ushort_t;
typedef __attribute__((ext_vector_type(8))) short bf16x8;
typedef __attribute__((ext_vector_type(4))) float f32x4;

#define BS 2
#define NS 48
#define NO 48
#define RD 512
#define MD 256
#define M1 (BS*NS*NO)   // 4608 rows of p1/p2
#define LN_EPS 1e-6f

// RNE (used in prep only — runs once, accuracy first)
__device__ __forceinline__ short f2bf(float f) {
    union { float f; unsigned u; } v; v.f = f;
    unsigned u = v.u;
    return (short)((u + 0x7fffu + ((u >> 16) & 1u)) >> 16);
}
// fast round-to-nearest (ties away): 2 VALU ops
__device__ __forceinline__ short f2bf_fast(float f) {
    union { float f; unsigned u; } v; v.f = f;
    return (short)((v.u + 0x8000u) >> 16);
}

// ---------------------------------------------------------------------------
// prep: pack W (K x N, f32 row-major) into MFMA fragment layout, bf16:
//   dst[((ntG*NKS + ksG)*64 + lane)*8 + e] = W[ksG*32 + (lane>>4)*8 + e][ntG*16 + (lane&15)]
// This layout serves BOTH the A and B operand roles of mfma_16x16x32 (the
// lane->(index,k) mapping is identical). One block per 64x64 tile, 512 thr.
// Blocks: 0-31 W1, 32-63 W2, 64-79 We.
// ---------------------------------------------------------------------------
__global__ __launch_bounds__(512) void prep_kernel(
    const float* __restrict__ W1, const float* __restrict__ W2,
    const float* __restrict__ We,
    ushort_t* __restrict__ w1F, ushort_t* __restrict__ w2F,
    ushort_t* __restrict__ weF)
{
    __shared__ float tile[64][65];
    int b = blockIdx.x;
    const float* src; ushort_t* dst; int NKS, kT, nT;
    if (b < 32)      { src = W1; dst = w1F; NKS = 16; kT = b >> 2;        nT = b & 3; }
    else if (b < 64) { src = W2; dst = w2F; NKS = 16; kT = (b - 32) >> 2; nT = b & 3; }
    else             { src = We; dst = weF; NKS = 8;  kT = (b - 64) >> 2; nT = b & 3; }
    int R0 = kT * 64, C0 = nT * 64;
    int tid = threadIdx.x;
#pragma unroll
    for (int pass = 0; pass < 2; ++pass) {
        int kl = pass * 32 + (tid >> 4);
        int nl = (tid & 15) * 4;
        float4 v = *reinterpret_cast<const float4*>(src + (size_t)(R0 + kl) * MD + C0 + nl);
        tile[kl][nl + 0] = v.x; tile[kl][nl + 1] = v.y;
        tile[kl][nl + 2] = v.z; tile[kl][nl + 3] = v.w;
    }
    __syncthreads();
    int f = tid >> 6, lane = tid & 63, lr = lane & 15, lg = lane >> 4;
    int ntl = f >> 1, ksl = f & 1;
    int ntG = (C0 >> 4) + ntl, ksG = (R0 >> 5) + ksl;
    bf16x8 v;
#pragma unroll
    for (int e = 0; e < 8; ++e)
        v[e] = f2bf(tile[ksl * 32 + lg * 8 + e][ntl * 16 + lr]);
    *reinterpret_cast<bf16x8*>(dst + ((size_t)(ntG * NKS + ksG) * 64 + lane) * 8) = v;
}

// ---------------------------------------------------------------------------
// stage1: P1 = rel @ W1 + b1, P2 = rel @ W2 + b2  (bf16 MFMA, fp32 out)
// 576 blocks: mt = b>>1, which = b&1. 256 threads = 4 waves, wave = 64 cols.
// ---------------------------------------------------------------------------
__global__ __launch_bounds__(256) void stage1_kernel(
    const float* __restrict__ rel,
    const ushort_t* __restrict__ w1F, const ushort_t* __restrict__ w2F,
    const float* __restrict__ b1, const float* __restrict__ b2,
    float* __restrict__ p1, float* __restrict__ p2)
{
    __shared__ __align__(16) char ldsA[16 * RD * 2];   // 16 KB
    int blk = blockIdx.x;
    int mt = blk >> 1, which = blk & 1;
    const ushort_t* wF = which ? w2F : w1F;
    const float* bias  = which ? b2 : b1;
    float* out         = which ? p2 : p1;
    int tid = threadIdx.x, wid = tid >> 6, lane = tid & 63;
    int lr = lane & 15, lg = lane >> 4;

#pragma unroll
    for (int it = 0; it < 8; ++it) {
        int rr = it * 2 + (tid >> 7);
        int c  = (tid & 127) * 4;
        float4 v = *reinterpret_cast<const float4*>(rel + (size_t)(mt * 16 + rr) * RD + c);
        short4 s;
        s.x = f2bf_fast(v.x); s.y = f2bf_fast(v.y);
        s.z = f2bf_fast(v.z); s.w = f2bf_fast(v.w);
        *reinterpret_cast<short4*>(ldsA + rr * (RD * 2) + ((c * 2) ^ ((rr & 7) << 4))) = s;
    }
    __syncthreads();

    int n0 = wid * 64;
    f32x4 acc[4] = {};
#pragma unroll
    for (int ks = 0; ks < 16; ++ks) {
        bf16x8 a = *reinterpret_cast<const bf16x8*>(
            ldsA + lr * (RD * 2) + ((ks * 64 + lg * 16) ^ ((lr & 7) << 4)));
#pragma unroll
        for (int nt = 0; nt < 4; ++nt) {
            int ntG = (n0 >> 4) + nt;
            bf16x8 bfr = *reinterpret_cast<const bf16x8*>(
                wF + ((size_t)(ntG * 16 + ks) * 64 + lane) * 8);
            acc[nt] = __builtin_amdgcn_mfma_f32_16x16x32_bf16(a, bfr, acc[nt], 0, 0, 0);
        }
    }
#pragma unroll
    for (int nt = 0; nt < 4; ++nt) {
        int col = n0 + nt * 16 + lr;
        float bv = bias[col];
#pragma unroll
        for (int r = 0; r < 4; ++r) {
            int orow = mt * 16 + lg * 4 + r;
            out[(size_t)orow * MD + col] = acc[nt][r] + bv;
        }
    }
}

// ---------------------------------------------------------------------------
// stage2 (TRANSPOSED): computes h^T = We^T * prod^T per (b,s,o1) block.
//   M-dim = n (256 output cols), N-dim = r (48 o2 rows), K = m (256).
// A = weF fragments (registers, coalesced L2 loads);
// B = prod rows from swizzled LDS (same read pattern as before).
// Output fragment: row = n (lg*4+reg), col = r (lr)  ->  LN reduction over n
// is lane-local + 2 shfl levels; LN apply is 1 FMA/elt; stores are float4
// with full 64B-line coverage.
// 512 threads = 8 waves; wave owns n-rows [wid*32, wid*32+32).
// ---------------------------------------------------------------------------
__global__ __launch_bounds__(512, 4) void stage2_kernel(
    const float* __restrict__ p1, const float* __restrict__ p2,
    const ushort_t* __restrict__ weF,
    const float* __restrict__ be, const float* __restrict__ gamma,
    const float* __restrict__ beta, float* __restrict__ out)
{
    __shared__ __align__(16) char ldsA[NO * MD * 2];   // 24576 B
    __shared__ float pS1[NO][8];
    __shared__ float pS2[NO][8];
    __shared__ float muS[NO];
    __shared__ float rsS[NO];

    int bid  = blockIdx.x;
    int grp  = (bid / NO) * NO;
    int tid  = threadIdx.x;
    int wid  = tid >> 6;
    int lane = tid & 63;
    int lr   = lane & 15;
    int lg   = lane >> 4;
    int m0w  = wid * 32;              // this wave's n-row base

    // ---- A fragments (weF), all 16, issued before staging to overlap ----
    bf16x8 afrag[2][8];
#pragma unroll
    for (int mt = 0; mt < 2; ++mt) {
        int ntG = (m0w >> 4) + mt;
#pragma unroll
        for (int ks = 0; ks < 8; ++ks)
            afrag[mt][ks] = *reinterpret_cast<const bf16x8*>(
                weF + ((size_t)(ntG * 8 + ks) * 64 + lane) * 8);
    }

    // ---- stage prod rows into LDS (coalesced 1KB reads, swizzled writes) ----
    const float* p1r = p1 + (size_t)bid * MD;
#pragma unroll
    for (int i = 0; i < 6; ++i) {
        int r  = i * 8 + wid;
        int m0 = lane * 4;
        float4 x = *reinterpret_cast<const float4*>(p1r + m0);
        float4 y = *reinterpret_cast<const float4*>(p2 + (size_t)(grp + r) * MD + m0);
        short4 s;
        s.x = f2bf_fast(x.x * y.x); s.y = f2bf_fast(x.y * y.y);
        s.z = f2bf_fast(x.z * y.z); s.w = f2bf_fast(x.w * y.w);
        *reinterpret_cast<short4*>(ldsA + r * (MD * 2) + ((m0 * 2) ^ ((r & 7) << 4))) = s;
    }
    __syncthreads();

    // ---- K-loop: A from regs, B from LDS ----
    f32x4 acc[2][3] = {};
#pragma unroll
    for (int ks = 0; ks < 8; ++ks) {
        bf16x8 b[3];
#pragma unroll
        for (int nt = 0; nt < 3; ++nt) {
            int r = nt * 16 + lr;
            b[nt] = *reinterpret_cast<const bf16x8*>(
                ldsA + r * (MD * 2) + ((ks * 64 + lg * 16) ^ ((r & 7) << 4)));
        }
#pragma unroll
        for (int mt = 0; mt < 2; ++mt)
#pragma unroll
            for (int nt = 0; nt < 3; ++nt)
                acc[mt][nt] = __builtin_amdgcn_mfma_f32_16x16x32_bf16(
                    afrag[mt][ks], b[nt], acc[mt][nt], 0, 0, 0);
    }

    // ---- add be (per-n = per row; float4 per M-tile) ----
#pragma unroll
    for (int mt = 0; mt < 2; ++mt) {
        float4 bev = *reinterpret_cast<const float4*>(be + m0w + mt * 16 + lg * 4);
#pragma unroll
        for (int nt = 0; nt < 3; ++nt) {
            acc[mt][nt][0] += bev.x; acc[mt][nt][1] += bev.y;
            acc[mt][nt][2] += bev.z; acc[mt][nt][3] += bev.w;
        }
    }

    // ---- LN partials: per col r, lane-local 8-sum + xor16 + xor32 ----
#pragma unroll
    for (int nt = 0; nt < 3; ++nt) {
        float s1 = 0.f, s2 = 0.f;
#pragma unroll
        for (int mt = 0; mt < 2; ++mt)
#pragma unroll
            for (int r = 0; r < 4; ++r) {
                float v = acc[mt][nt][r];
                s1 += v; s2 += v * v;
            }
        s1 += __shfl_xor(s1, 16); s2 += __shfl_xor(s2, 16);
        s1 += __shfl_xor(s1, 32); s2 += __shfl_xor(s2, 32);
        if (lane < 16) {
            pS1[nt * 16 + lane][wid] = s1;
            pS2[nt * 16 + lane][wid] = s2;
        }
    }
    __syncthreads();

    // ---- finalize stats: one thread per col ----
    if (tid < NO) {
        f32x4 a0 = *reinterpret_cast<const f32x4*>(&pS1[tid][0]);
        f32x4 a1 = *reinterpret_cast<const f32x4*>(&pS1[tid][4]);
        f32x4 b0 = *reinterpret_cast<const f32x4*>(&pS2[tid][0]);
        f32x4 b1v = *reinterpret_cast<const f32x4*>(&pS2[tid][4]);
        float S1 = a0[0]+a0[1]+a0[2]+a0[3] + a1[0]+a1[1]+a1[2]+a1[3];
        float S2 = b0[0]+b0[1]+b0[2]+b0[3] + b1v[0]+b1v[1]+b1v[2]+b1v[3];
        float m  = S1 * (1.0f / MD);
        float var = S2 * (1.0f / MD) - m * m;
        muS[tid] = m;
        rsS[tid] = rsqrtf(var + LN_EPS);
    }
    __syncthreads();

    // ---- LN apply + float4 stores (full-line coalesced) ----
    size_t ob = (size_t)bid * NO * MD;
#pragma unroll
    for (int nt = 0; nt < 3; ++nt) {
        int r = nt * 16 + lr;
        float sc = rsS[r] * gamma[r];
        float of = beta[r] - muS[r] * sc;
#pragma unroll
        for (int mt = 0; mt < 2; ++mt) {
            float4 o;
            o.x = acc[mt][nt][0] * sc + of;
            o.y = acc[mt][nt][1] * sc + of;
            o.z = acc[mt][nt][2] * sc + of;
            o.w = acc[mt][nt][3] * sc + of;
            *reinterpret_cast<float4*>(out + ob + (size_t)r * MD + m0w + mt * 16 + lg * 4) = o;
        }
    }
}

// ---------------------------------------------------------------------------
extern "C" void kernel_launch(void* const* d_in, const int* in_sizes, int n_in,
                              void* d_out, int out_size, void* d_ws, size_t ws_size,
                              hipStream_t stream) {
    const float* rel   = (const float*)d_in[0];
    const float* W1    = (const float*)d_in[1];
    const float* b1    = (const float*)d_in[2];
    const float* W2    = (const float*)d_in[3];
    const float* b2    = (const float*)d_in[4];
    const float* We    = (const float*)d_in[5];
    const float* be    = (const float*)d_in[6];
    const float* gamma = (const float*)d_in[7];
    const float* beta  = (const float*)d_in[8];
    float* out = (float*)d_out;

    char* ws = (char*)d_ws;
    // ws layout (bytes): w1F 512K | w2F 512K | weF 128K | p1 4.5M | p2 4.5M
    ushort_t* w1F = (ushort_t*)(ws);
    ushort_t* w2F = (ushort_t*)(ws + 524288);
    ushort_t* weF = (ushort_t*)(ws + 1048576);
    float*    p1  = (float*)   (ws + 1179648);
    float*    p2  = (float*)   (ws + 1179648 + 4718592);

    prep_kernel<<<80, 512, 0, stream>>>(W1, W2, We, w1F, w2F, weF);
    stage1_kernel<<<576, 256, 0, stream>>>(rel, w1F, w2F, b1, b2, p1, p2);
    stage2_kernel<<<M1, 512, 0, stream>>>(p1, p2, weF, be, gamma, beta, out);
}

// Round 9
// 96.664 us; speedup vs baseline: 1.8808x; 1.0352x over previous
//
#include <hip/hip_runtime.h>

typedef unsigned short ushort_t;
typedef __attribute__((ext_vector_type(8))) short bf16x8;
typedef __attribute__((ext_vector_type(4))) float f32x4;

#define BS 2
#define NS 48
#define NO 48
#define RD 512
#define MD 256
#define M1 (BS*NS*NO)   // 4608 (b,s,o1) rows
#define LN_EPS 1e-6f

// RNE
__device__ __forceinline__ short f2bf(float f) {
    union { float f; unsigned u; } v; v.f = f;
    unsigned u = v.u;
    return (short)((u + 0x7fffu + ((u >> 16) & 1u)) >> 16);
}
// fast round-to-nearest (ties away): 2 VALU ops
__device__ __forceinline__ short f2bf_fast(float f) {
    union { float f; unsigned u; } v; v.f = f;
    return (short)((v.u + 0x8000u) >> 16);
}

// ---------------------------------------------------------------------------
// prep: pack W (K x N, f32 row-major) into MFMA fragment layout, bf16:
//   dst[((ntG*NKS + ksG)*64 + lane)*8 + e] = W[ksG*32 + (lane>>4)*8 + e][ntG*16 + (lane&15)]
// Serves both A and B operand roles of mfma_16x16x32 (identical lane maps).
// Blocks: 0-31 W1, 32-63 W2, 64-79 We. 512 threads.
// ---------------------------------------------------------------------------
__global__ __launch_bounds__(512) void prep_kernel(
    const float* __restrict__ W1, const float* __restrict__ W2,
    const float* __restrict__ We,
    ushort_t* __restrict__ w1F, ushort_t* __restrict__ w2F,
    ushort_t* __restrict__ weF)
{
    __shared__ float tile[64][65];
    int b = blockIdx.x;
    const float* src; ushort_t* dst; int NKS, kT, nT;
    if (b < 32)      { src = W1; dst = w1F; NKS = 16; kT = b >> 2;        nT = b & 3; }
    else if (b < 64) { src = W2; dst = w2F; NKS = 16; kT = (b - 32) >> 2; nT = b & 3; }
    else             { src = We; dst = weF; NKS = 8;  kT = (b - 64) >> 2; nT = b & 3; }
    int R0 = kT * 64, C0 = nT * 64;
    int tid = threadIdx.x;
#pragma unroll
    for (int pass = 0; pass < 2; ++pass) {
        int kl = pass * 32 + (tid >> 4);
        int nl = (tid & 15) * 4;
        float4 v = *reinterpret_cast<const float4*>(src + (size_t)(R0 + kl) * MD + C0 + nl);
        tile[kl][nl + 0] = v.x; tile[kl][nl + 1] = v.y;
        tile[kl][nl + 2] = v.z; tile[kl][nl + 3] = v.w;
    }
    __syncthreads();
    int f = tid >> 6, lane = tid & 63, lr = lane & 15, lg = lane >> 4;
    int ntl = f >> 1, ksl = f & 1;
    int ntG = (C0 >> 4) + ntl, ksG = (R0 >> 5) + ksl;
    bf16x8 v;
#pragma unroll
    for (int e = 0; e < 8; ++e)
        v[e] = f2bf(tile[ksl * 32 + lg * 8 + e][ntl * 16 + lr]);
    *reinterpret_cast<bf16x8*>(dst + ((size_t)(ntG * NKS + ksG) * 64 + lane) * 8) = v;
}

// ---------------------------------------------------------------------------
// stage1: P1 = rel @ W1 + b1, P2 = rel @ W2 + b2  (bf16 MFMA, fp32 out)
// 576 blocks: mt = b>>1, which = b&1. 256 threads = 4 waves, wave = 64 cols.
// ---------------------------------------------------------------------------
__global__ __launch_bounds__(256) void stage1_kernel(
    const float* __restrict__ rel,
    const ushort_t* __restrict__ w1F, const ushort_t* __restrict__ w2F,
    const float* __restrict__ b1, const float* __restrict__ b2,
    float* __restrict__ p1, float* __restrict__ p2)
{
    __shared__ __align__(16) char ldsA[16 * RD * 2];   // 16 KB
    int blk = blockIdx.x;
    int mt = blk >> 1, which = blk & 1;
    const ushort_t* wF = which ? w2F : w1F;
    const float* bias  = which ? b2 : b1;
    float* out         = which ? p2 : p1;
    int tid = threadIdx.x, wid = tid >> 6, lane = tid & 63;
    int lr = lane & 15, lg = lane >> 4;

#pragma unroll
    for (int it = 0; it < 8; ++it) {
        int rr = it * 2 + (tid >> 7);
        int c  = (tid & 127) * 4;
        float4 v = *reinterpret_cast<const float4*>(rel + (size_t)(mt * 16 + rr) * RD + c);
        short4 s;
        s.x = f2bf_fast(v.x); s.y = f2bf_fast(v.y);
        s.z = f2bf_fast(v.z); s.w = f2bf_fast(v.w);
        *reinterpret_cast<short4*>(ldsA + rr * (RD * 2) + ((c * 2) ^ ((rr & 7) << 4))) = s;
    }
    __syncthreads();

    int n0 = wid * 64;
    f32x4 acc[4] = {};
#pragma unroll
    for (int ks = 0; ks < 16; ++ks) {
        bf16x8 a = *reinterpret_cast<const bf16x8*>(
            ldsA + lr * (RD * 2) + ((ks * 64 + lg * 16) ^ ((lr & 7) << 4)));
#pragma unroll
        for (int nt = 0; nt < 4; ++nt) {
            int ntG = (n0 >> 4) + nt;
            bf16x8 bfr = *reinterpret_cast<const bf16x8*>(
                wF + ((size_t)(ntG * 16 + ks) * 64 + lane) * 8);
            acc[nt] = __builtin_amdgcn_mfma_f32_16x16x32_bf16(a, bfr, acc[nt], 0, 0, 0);
        }
    }
#pragma unroll
    for (int nt = 0; nt < 4; ++nt) {
        int col = n0 + nt * 16 + lr;
        float bv = bias[col];
#pragma unroll
        for (int r = 0; r < 4; ++r) {
            int orow = mt * 16 + lg * 4 + r;
            out[(size_t)orow * MD + col] = acc[nt][r] + bv;
        }
    }
}

// ---------------------------------------------------------------------------
// stage2 (R5 structure VERBATIM + XCD swizzle only): one block per (b,s,o1),
// transposed GEMM h^T = We^T * prod^T.
// bid = (d&7)*576 + (d>>3): bijective; with d%8 XCD round-robin this puts all
// 48 blocks of a (b,s) group (sharing 48 p2 rows) on ONE XCD's L2.
// 512 threads = 8 waves; wave owns n-rows [wid*32, wid*32+32).
// ---------------------------------------------------------------------------
__global__ __launch_bounds__(512, 4) void stage2_kernel(
    const float* __restrict__ p1, const float* __restrict__ p2,
    const ushort_t* __restrict__ weF,
    const float* __restrict__ be, const float* __restrict__ gamma,
    const float* __restrict__ beta, float* __restrict__ out)
{
    __shared__ __align__(16) char ldsA[NO * MD * 2];   // 24576 B
    __shared__ float pS1[NO][8];
    __shared__ float pS2[NO][8];
    __shared__ float muS[NO];
    __shared__ float rsS[NO];

    int d    = blockIdx.x;
    int bid  = (d & 7) * 576 + (d >> 3);   // 4608 = 8*576, bijective
    int grp  = (bid / NO) * NO;
    int tid  = threadIdx.x;
    int wid  = tid >> 6;
    int lane = tid & 63;
    int lr   = lane & 15;
    int lg   = lane >> 4;
    int m0w  = wid * 32;              // wave's n-row base

    // ---- A fragments (weF), all 16, issued before staging to overlap ----
    bf16x8 afrag[2][8];
#pragma unroll
    for (int mt = 0; mt < 2; ++mt) {
        int ntG = (m0w >> 4) + mt;
#pragma unroll
        for (int ks = 0; ks < 8; ++ks)
            afrag[mt][ks] = *reinterpret_cast<const bf16x8*>(
                weF + ((size_t)(ntG * 8 + ks) * 64 + lane) * 8);
    }

    // ---- stage prod rows into LDS (coalesced 1KB reads, swizzled writes) ----
    const float* p1r = p1 + (size_t)bid * MD;
#pragma unroll
    for (int i = 0; i < 6; ++i) {
        int r  = i * 8 + wid;
        int m0 = lane * 4;
        float4 x = *reinterpret_cast<const float4*>(p1r + m0);
        float4 y = *reinterpret_cast<const float4*>(p2 + (size_t)(grp + r) * MD + m0);
        short4 s;
        s.x = f2bf_fast(x.x * y.x); s.y = f2bf_fast(x.y * y.y);
        s.z = f2bf_fast(x.z * y.z); s.w = f2bf_fast(x.w * y.w);
        *reinterpret_cast<short4*>(ldsA + r * (MD * 2) + ((m0 * 2) ^ ((r & 7) << 4))) = s;
    }
    __syncthreads();

    // ---- K-loop: A from regs, B from LDS ----
    f32x4 acc[2][3] = {};
#pragma unroll
    for (int ks = 0; ks < 8; ++ks) {
        bf16x8 b[3];
#pragma unroll
        for (int nt = 0; nt < 3; ++nt) {
            int r = nt * 16 + lr;
            b[nt] = *reinterpret_cast<const bf16x8*>(
                ldsA + r * (MD * 2) + ((ks * 64 + lg * 16) ^ ((r & 7) << 4)));
        }
#pragma unroll
        for (int mt = 0; mt < 2; ++mt)
#pragma unroll
            for (int nt = 0; nt < 3; ++nt)
                acc[mt][nt] = __builtin_amdgcn_mfma_f32_16x16x32_bf16(
                    afrag[mt][ks], b[nt], acc[mt][nt], 0, 0, 0);
    }

    // ---- add be (per-n = per row; float4 per M-tile) ----
#pragma unroll
    for (int mt = 0; mt < 2; ++mt) {
        float4 bev = *reinterpret_cast<const float4*>(be + m0w + mt * 16 + lg * 4);
#pragma unroll
        for (int nt = 0; nt < 3; ++nt) {
            acc[mt][nt][0] += bev.x; acc[mt][nt][1] += bev.y;
            acc[mt][nt][2] += bev.z; acc[mt][nt][3] += bev.w;
        }
    }

    // ---- LN partials: per col r, lane-local 8-sum + xor16 + xor32 ----
#pragma unroll
    for (int nt = 0; nt < 3; ++nt) {
        float s1 = 0.f, s2 = 0.f;
#pragma unroll
        for (int mt = 0; mt < 2; ++mt)
#pragma unroll
            for (int r = 0; r < 4; ++r) {
                float v = acc[mt][nt][r];
                s1 += v; s2 += v * v;
            }
        s1 += __shfl_xor(s1, 16); s2 += __shfl_xor(s2, 16);
        s1 += __shfl_xor(s1, 32); s2 += __shfl_xor(s2, 32);
        if (lane < 16) {
            pS1[nt * 16 + lane][wid] = s1;
            pS2[nt * 16 + lane][wid] = s2;
        }
    }
    __syncthreads();

    // ---- finalize stats: one thread per col ----
    if (tid < NO) {
        f32x4 a0 = *reinterpret_cast<const f32x4*>(&pS1[tid][0]);
        f32x4 a1 = *reinterpret_cast<const f32x4*>(&pS1[tid][4]);
        f32x4 b0 = *reinterpret_cast<const f32x4*>(&pS2[tid][0]);
        f32x4 b1v = *reinterpret_cast<const f32x4*>(&pS2[tid][4]);
        float S1 = a0[0]+a0[1]+a0[2]+a0[3] + a1[0]+a1[1]+a1[2]+a1[3];
        float S2 = b0[0]+b0[1]+b0[2]+b0[3] + b1v[0]+b1v[1]+b1v[2]+b1v[3];
        float m  = S1 * (1.0f / MD);
        float var = S2 * (1.0f / MD) - m * m;
        muS[tid] = m;
        rsS[tid] = rsqrtf(var + LN_EPS);
    }
    __syncthreads();

    // ---- LN apply + float4 stores (full-line coalesced) ----
    size_t ob = (size_t)bid * NO * MD;
#pragma unroll
    for (int nt = 0; nt < 3; ++nt) {
        int r = nt * 16 + lr;
        float sc = rsS[r] * gamma[r];
        float of = beta[r] - muS[r] * sc;
#pragma unroll
        for (int mt = 0; mt < 2; ++mt) {
            float4 o;
            o.x = acc[mt][nt][0] * sc + of;
            o.y = acc[mt][nt][1] * sc + of;
            o.z = acc[mt][nt][2] * sc + of;
            o.w = acc[mt][nt][3] * sc + of;
            *reinterpret_cast<float4*>(out + ob + (size_t)r * MD + m0w + mt * 16 + lg * 4) = o;
        }
    }
}

// ---------------------------------------------------------------------------
extern "C" void kernel_launch(void* const* d_in, const int* in_sizes, int n_in,
                              void* d_out, int out_size, void* d_ws, size_t ws_size,
                              hipStream_t stream) {
    const float* rel   = (const float*)d_in[0];
    const float* W1    = (const float*)d_in[1];
    const float* b1    = (const float*)d_in[2];
    const float* W2    = (const float*)d_in[3];
    const float* b2    = (const float*)d_in[4];
    const float* We    = (const float*)d_in[5];
    const float* be    = (const float*)d_in[6];
    const float* gamma = (const float*)d_in[7];
    const float* beta  = (const float*)d_in[8];
    float* out = (float*)d_out;

    char* ws = (char*)d_ws;
    // ws layout (bytes): w1F 512K | w2F 512K | weF 128K | p1 4.5M | p2 4.5M
    ushort_t* w1F = (ushort_t*)(ws);
    ushort_t* w2F = (ushort_t*)(ws + 524288);
    ushort_t* weF = (ushort_t*)(ws + 1048576);
    float*    p1  = (float*)   (ws + 1179648);
    float*    p2  = (float*)   (ws + 1179648 + 4718592);

    prep_kernel<<<80, 512, 0, stream>>>(W1, W2, We, w1F, w2F, weF);
    stage1_kernel<<<576, 256, 0, stream>>>(rel, w1F, w2F, b1, b2, p1, p2);
    stage2_kernel<<<M1, 512, 0, stream>>>(p1, p2, weF, be, gamma, beta, out);
}

// Round 10
// 83.668 us; speedup vs baseline: 2.1729x; 1.1553x over previous
//
#include <hip/hip_runtime.h>

typedef unsigned short ushort_t;
typedef __attribute__((ext_vector_type(8))) short bf16x8;
typedef __attribute__((ext_vector_type(4))) float f32x4;

#define BS 2
#define NS 48
#define NO 48
#define RD 512
#define MD 256
#define M1 (BS*NS*NO)   // 4608 (b,s,o1) rows
#define LN_EPS 1e-6f

// RNE
__device__ __forceinline__ short f2bf(float f) {
    union { float f; unsigned u; } v; v.f = f;
    unsigned u = v.u;
    return (short)((u + 0x7fffu + ((u >> 16) & 1u)) >> 16);
}
// fast round-to-nearest (ties away): 2 VALU ops
__device__ __forceinline__ short f2bf_fast(float f) {
    union { float f; unsigned u; } v; v.f = f;
    return (short)((v.u + 0x8000u) >> 16);
}

// ---------------------------------------------------------------------------
// prep: pack W (K x N, f32 row-major) into MFMA fragment layout, bf16:
//   dst[((ntG*NKS + ksG)*64 + lane)*8 + e] = W[ksG*32 + (lane>>4)*8 + e][ntG*16 + (lane&15)]
// Serves both A and B operand roles of mfma_16x16x32 (identical lane maps).
// Blocks: 0-31 W1, 32-63 W2, 64-79 We. 512 threads.
// ---------------------------------------------------------------------------
__global__ __launch_bounds__(512) void prep_kernel(
    const float* __restrict__ W1, const float* __restrict__ W2,
    const float* __restrict__ We,
    ushort_t* __restrict__ w1F, ushort_t* __restrict__ w2F,
    ushort_t* __restrict__ weF)
{
    __shared__ float tile[64][65];
    int b = blockIdx.x;
    const float* src; ushort_t* dst; int NKS, kT, nT;
    if (b < 32)      { src = W1; dst = w1F; NKS = 16; kT = b >> 2;        nT = b & 3; }
    else if (b < 64) { src = W2; dst = w2F; NKS = 16; kT = (b - 32) >> 2; nT = b & 3; }
    else             { src = We; dst = weF; NKS = 8;  kT = (b - 64) >> 2; nT = b & 3; }
    int R0 = kT * 64, C0 = nT * 64;
    int tid = threadIdx.x;
#pragma unroll
    for (int pass = 0; pass < 2; ++pass) {
        int kl = pass * 32 + (tid >> 4);
        int nl = (tid & 15) * 4;
        float4 v = *reinterpret_cast<const float4*>(src + (size_t)(R0 + kl) * MD + C0 + nl);
        tile[kl][nl + 0] = v.x; tile[kl][nl + 1] = v.y;
        tile[kl][nl + 2] = v.z; tile[kl][nl + 3] = v.w;
    }
    __syncthreads();
    int f = tid >> 6, lane = tid & 63, lr = lane & 15, lg = lane >> 4;
    int ntl = f >> 1, ksl = f & 1;
    int ntG = (C0 >> 4) + ntl, ksG = (R0 >> 5) + ksl;
    bf16x8 v;
#pragma unroll
    for (int e = 0; e < 8; ++e)
        v[e] = f2bf(tile[ksl * 32 + lg * 8 + e][ntl * 16 + lr]);
    *reinterpret_cast<bf16x8*>(dst + ((size_t)(ntG * NKS + ksG) * 64 + lane) * 8) = v;
}

// ---------------------------------------------------------------------------
// stage1: P1 = rel @ W1 + b1, P2 = rel @ W2 + b2  (bf16 MFMA, fp32 out)
// 576 blocks: mt = b>>1, which = b&1. 256 threads = 4 waves, wave = 64 cols.
// ---------------------------------------------------------------------------
__global__ __launch_bounds__(256) void stage1_kernel(
    const float* __restrict__ rel,
    const ushort_t* __restrict__ w1F, const ushort_t* __restrict__ w2F,
    const float* __restrict__ b1, const float* __restrict__ b2,
    float* __restrict__ p1, float* __restrict__ p2)
{
    __shared__ __align__(16) char ldsA[16 * RD * 2];   // 16 KB
    int blk = blockIdx.x;
    int mt = blk >> 1, which = blk & 1;
    const ushort_t* wF = which ? w2F : w1F;
    const float* bias  = which ? b2 : b1;
    float* out         = which ? p2 : p1;
    int tid = threadIdx.x, wid = tid >> 6, lane = tid & 63;
    int lr = lane & 15, lg = lane >> 4;

#pragma unroll
    for (int it = 0; it < 8; ++it) {
        int rr = it * 2 + (tid >> 7);
        int c  = (tid & 127) * 4;
        float4 v = *reinterpret_cast<const float4*>(rel + (size_t)(mt * 16 + rr) * RD + c);
        short4 s;
        s.x = f2bf_fast(v.x); s.y = f2bf_fast(v.y);
        s.z = f2bf_fast(v.z); s.w = f2bf_fast(v.w);
        *reinterpret_cast<short4*>(ldsA + rr * (RD * 2) + ((c * 2) ^ ((rr & 7) << 4))) = s;
    }
    __syncthreads();

    int n0 = wid * 64;
    f32x4 acc[4] = {};
#pragma unroll
    for (int ks = 0; ks < 16; ++ks) {
        bf16x8 a = *reinterpret_cast<const bf16x8*>(
            ldsA + lr * (RD * 2) + ((ks * 64 + lg * 16) ^ ((lr & 7) << 4)));
#pragma unroll
        for (int nt = 0; nt < 4; ++nt) {
            int ntG = (n0 >> 4) + nt;
            bf16x8 bfr = *reinterpret_cast<const bf16x8*>(
                wF + ((size_t)(ntG * 16 + ks) * 64 + lane) * 8);
            acc[nt] = __builtin_amdgcn_mfma_f32_16x16x32_bf16(a, bfr, acc[nt], 0, 0, 0);
        }
    }
#pragma unroll
    for (int nt = 0; nt < 4; ++nt) {
        int col = n0 + nt * 16 + lr;
        float bv = bias[col];
#pragma unroll
        for (int r = 0; r < 4; ++r) {
            int orow = mt * 16 + lg * 4 + r;
            out[(size_t)orow * MD + col] = acc[nt][r] + bv;
        }
    }
}

// ---------------------------------------------------------------------------
// stage2 (R9 base; epilogue reworked): one block per (b,s,o1), transposed
// GEMM h^T = We^T * prod^T.  XCD swizzle for group L2 locality.
// NEW: after LN apply, the output tile is transposed through LDS in three
// 16-row x 256-col fp32 chunks (XOR-swizzled, conflict-free) so each global
// store instruction is a wave-contiguous 1KB burst (fill-kernel pattern),
// instead of 16 x 64B lines at 1KB stride.
// ---------------------------------------------------------------------------
__global__ __launch_bounds__(512, 4) void stage2_kernel(
    const float* __restrict__ p1, const float* __restrict__ p2,
    const ushort_t* __restrict__ weF,
    const float* __restrict__ be, const float* __restrict__ gamma,
    const float* __restrict__ beta, float* __restrict__ out)
{
    __shared__ __align__(16) char ldsA[NO * MD * 2];   // 24576 B
    __shared__ float pS1[NO][8];
    __shared__ float pS2[NO][8];
    __shared__ float muS[NO];
    __shared__ float rsS[NO];

    int d    = blockIdx.x;
    int bid  = (d & 7) * 576 + (d >> 3);   // 4608 = 8*576, bijective
    int grp  = (bid / NO) * NO;
    int tid  = threadIdx.x;
    int wid  = tid >> 6;
    int lane = tid & 63;
    int lr   = lane & 15;
    int lg   = lane >> 4;
    int m0w  = wid * 32;              // wave's n-row base

    // ---- A fragments (weF), all 16, issued before staging to overlap ----
    bf16x8 afrag[2][8];
#pragma unroll
    for (int mt = 0; mt < 2; ++mt) {
        int ntG = (m0w >> 4) + mt;
#pragma unroll
        for (int ks = 0; ks < 8; ++ks)
            afrag[mt][ks] = *reinterpret_cast<const bf16x8*>(
                weF + ((size_t)(ntG * 8 + ks) * 64 + lane) * 8);
    }

    // ---- stage prod rows into LDS (coalesced 1KB reads, swizzled writes) ----
    const float* p1r = p1 + (size_t)bid * MD;
#pragma unroll
    for (int i = 0; i < 6; ++i) {
        int r  = i * 8 + wid;
        int m0 = lane * 4;
        float4 x = *reinterpret_cast<const float4*>(p1r + m0);
        float4 y = *reinterpret_cast<const float4*>(p2 + (size_t)(grp + r) * MD + m0);
        short4 s;
        s.x = f2bf_fast(x.x * y.x); s.y = f2bf_fast(x.y * y.y);
        s.z = f2bf_fast(x.z * y.z); s.w = f2bf_fast(x.w * y.w);
        *reinterpret_cast<short4*>(ldsA + r * (MD * 2) + ((m0 * 2) ^ ((r & 7) << 4))) = s;
    }
    __syncthreads();

    // ---- K-loop: A from regs, B from LDS ----
    f32x4 acc[2][3] = {};
#pragma unroll
    for (int ks = 0; ks < 8; ++ks) {
        bf16x8 b[3];
#pragma unroll
        for (int nt = 0; nt < 3; ++nt) {
            int r = nt * 16 + lr;
            b[nt] = *reinterpret_cast<const bf16x8*>(
                ldsA + r * (MD * 2) + ((ks * 64 + lg * 16) ^ ((r & 7) << 4)));
        }
#pragma unroll
        for (int mt = 0; mt < 2; ++mt)
#pragma unroll
            for (int nt = 0; nt < 3; ++nt)
                acc[mt][nt] = __builtin_amdgcn_mfma_f32_16x16x32_bf16(
                    afrag[mt][ks], b[nt], acc[mt][nt], 0, 0, 0);
    }

    // ---- add be (per-n = per row; float4 per M-tile) ----
#pragma unroll
    for (int mt = 0; mt < 2; ++mt) {
        float4 bev = *reinterpret_cast<const float4*>(be + m0w + mt * 16 + lg * 4);
#pragma unroll
        for (int nt = 0; nt < 3; ++nt) {
            acc[mt][nt][0] += bev.x; acc[mt][nt][1] += bev.y;
            acc[mt][nt][2] += bev.z; acc[mt][nt][3] += bev.w;
        }
    }

    // ---- LN partials: per col r, lane-local 8-sum + xor16 + xor32 ----
#pragma unroll
    for (int nt = 0; nt < 3; ++nt) {
        float s1 = 0.f, s2 = 0.f;
#pragma unroll
        for (int mt = 0; mt < 2; ++mt)
#pragma unroll
            for (int r = 0; r < 4; ++r) {
                float v = acc[mt][nt][r];
                s1 += v; s2 += v * v;
            }
        s1 += __shfl_xor(s1, 16); s2 += __shfl_xor(s2, 16);
        s1 += __shfl_xor(s1, 32); s2 += __shfl_xor(s2, 32);
        if (lane < 16) {
            pS1[nt * 16 + lane][wid] = s1;
            pS2[nt * 16 + lane][wid] = s2;
        }
    }
    __syncthreads();

    // ---- finalize stats: one thread per col ----
    if (tid < NO) {
        f32x4 a0 = *reinterpret_cast<const f32x4*>(&pS1[tid][0]);
        f32x4 a1 = *reinterpret_cast<const f32x4*>(&pS1[tid][4]);
        f32x4 b0 = *reinterpret_cast<const f32x4*>(&pS2[tid][0]);
        f32x4 b1v = *reinterpret_cast<const f32x4*>(&pS2[tid][4]);
        float S1 = a0[0]+a0[1]+a0[2]+a0[3] + a1[0]+a1[1]+a1[2]+a1[3];
        float S2 = b0[0]+b0[1]+b0[2]+b0[3] + b1v[0]+b1v[1]+b1v[2]+b1v[3];
        float m  = S1 * (1.0f / MD);
        float var = S2 * (1.0f / MD) - m * m;
        muS[tid] = m;
        rsS[tid] = rsqrtf(var + LN_EPS);
    }
    __syncthreads();

    // ---- epilogue: LN apply -> LDS transpose (16-row chunks) -> contiguous
    //      1KB wave stores. ldsA is dead after the K-loop (fenced by the two
    //      barriers above); reuse it as fp32 [16][256] (16 KB).
    char* bufF = ldsA;
    size_t ob = (size_t)bid * NO * MD;
#pragma unroll
    for (int nt = 0; nt < 3; ++nt) {
        int r = nt * 16 + lr;
        float sc = rsS[r] * gamma[r];
        float of = beta[r] - muS[r] * sc;
#pragma unroll
        for (int mt = 0; mt < 2; ++mt) {
            float4 o;
            o.x = acc[mt][nt][0] * sc + of;
            o.y = acc[mt][nt][1] * sc + of;
            o.z = acc[mt][nt][2] * sc + of;
            o.w = acc[mt][nt][3] * sc + of;
            int n4 = (m0w + mt * 16 + lg * 4) * 4;           // byte offset of n in row
            *reinterpret_cast<float4*>(
                bufF + lr * 1024 + (n4 ^ ((lr & 7) << 4))) = o;
        }
        __syncthreads();   // chunk staged (also fences previous chunk's reads)
#pragma unroll
        for (int j = 0; j < 2; ++j) {
            int rl = wid * 2 + j;     // 16 rows, 2 per wave
            float4 o = *reinterpret_cast<const float4*>(
                bufF + rl * 1024 + ((lane * 16) ^ ((rl & 7) << 4)));
            *reinterpret_cast<float4*>(
                out + ob + (size_t)(nt * 16 + rl) * MD + lane * 4) = o;
        }
        __syncthreads();   // protect bufF before next chunk overwrites
    }
}

// ---------------------------------------------------------------------------
extern "C" void kernel_launch(void* const* d_in, const int* in_sizes, int n_in,
                              void* d_out, int out_size, void* d_ws, size_t ws_size,
                              hipStream_t stream) {
    const float* rel   = (const float*)d_in[0];
    const float* W1    = (const float*)d_in[1];
    const float* b1    = (const float*)d_in[2];
    const float* W2    = (const float*)d_in[3];
    const float* b2    = (const float*)d_in[4];
    const float* We    = (const float*)d_in[5];
    const float* be    = (const float*)d_in[6];
    const float* gamma = (const float*)d_in[7];
    const float* beta  = (const float*)d_in[8];
    float* out = (float*)d_out;

    char* ws = (char*)d_ws;
    // ws layout (bytes): w1F 512K | w2F 512K | weF 128K | p1 4.5M | p2 4.5M
    ushort_t* w1F = (ushort_t*)(ws);
    ushort_t* w2F = (ushort_t*)(ws + 524288);
    ushort_t* weF = (ushort_t*)(ws + 1048576);
    float*    p1  = (float*)   (ws + 1179648);
    float*    p2  = (float*)   (ws + 1179648 + 4718592);

    prep_kernel<<<80, 512, 0, stream>>>(W1, W2, We, w1F, w2F, weF);
    stage1_kernel<<<576, 256, 0, stream>>>(rel, w1F, w2F, b1, b2, p1, p2);
    stage2_kernel<<<M1, 512, 0, stream>>>(p1, p2, weF, be, gamma, beta, out);
}

// Round 11
// 82.764 us; speedup vs baseline: 2.1967x; 1.0109x over previous
//
#include <hip/hip_runtime.h>

typedef unsigned short ushort_t;
typedef __attribute__((ext_vector_type(8))) short bf16x8;
typedef __attribute__((ext_vector_type(4))) float f32x4;

#define BS 2
#define NS 48
#define NO 48
#define RD 512
#define MD 256
#define M1 (BS*NS*NO)   // 4608 (b,s,o1) rows
#define LN_EPS 1e-6f

// RNE
__device__ __forceinline__ short f2bf(float f) {
    union { float f; unsigned u; } v; v.f = f;
    unsigned u = v.u;
    return (short)((u + 0x7fffu + ((u >> 16) & 1u)) >> 16);
}
// fast round-to-nearest (ties away): 2 VALU ops
__device__ __forceinline__ short f2bf_fast(float f) {
    union { float f; unsigned u; } v; v.f = f;
    return (short)((v.u + 0x8000u) >> 16);
}

// ---------------------------------------------------------------------------
// prep: pack W (K x N, f32 row-major) into MFMA fragment layout, bf16:
//   dst[((ntG*NKS + ksG)*64 + lane)*8 + e] = W[ksG*32 + (lane>>4)*8 + e][ntG*16 + (lane&15)]
// Serves both A and B operand roles of mfma_16x16x32 (identical lane maps).
// Blocks: 0-31 W1, 32-63 W2, 64-79 We. 512 threads.
// ---------------------------------------------------------------------------
__global__ __launch_bounds__(512) void prep_kernel(
    const float* __restrict__ W1, const float* __restrict__ W2,
    const float* __restrict__ We,
    ushort_t* __restrict__ w1F, ushort_t* __restrict__ w2F,
    ushort_t* __restrict__ weF)
{
    __shared__ float tile[64][65];
    int b = blockIdx.x;
    const float* src; ushort_t* dst; int NKS, kT, nT;
    if (b < 32)      { src = W1; dst = w1F; NKS = 16; kT = b >> 2;        nT = b & 3; }
    else if (b < 64) { src = W2; dst = w2F; NKS = 16; kT = (b - 32) >> 2; nT = b & 3; }
    else             { src = We; dst = weF; NKS = 8;  kT = (b - 64) >> 2; nT = b & 3; }
    int R0 = kT * 64, C0 = nT * 64;
    int tid = threadIdx.x;
#pragma unroll
    for (int pass = 0; pass < 2; ++pass) {
        int kl = pass * 32 + (tid >> 4);
        int nl = (tid & 15) * 4;
        float4 v = *reinterpret_cast<const float4*>(src + (size_t)(R0 + kl) * MD + C0 + nl);
        tile[kl][nl + 0] = v.x; tile[kl][nl + 1] = v.y;
        tile[kl][nl + 2] = v.z; tile[kl][nl + 3] = v.w;
    }
    __syncthreads();
    int f = tid >> 6, lane = tid & 63, lr = lane & 15, lg = lane >> 4;
    int ntl = f >> 1, ksl = f & 1;
    int ntG = (C0 >> 4) + ntl, ksG = (R0 >> 5) + ksl;
    bf16x8 v;
#pragma unroll
    for (int e = 0; e < 8; ++e)
        v[e] = f2bf(tile[ksl * 32 + lg * 8 + e][ntl * 16 + lr]);
    *reinterpret_cast<bf16x8*>(dst + ((size_t)(ntG * NKS + ksG) * 64 + lane) * 8) = v;
}

// ---------------------------------------------------------------------------
// stage1: P1 = rel @ W1 + b1, P2 = rel @ W2 + b2  (bf16 MFMA, fp32 out)
// 576 blocks: mt = b>>1, which = b&1. 256 threads = 4 waves, wave = 64 cols.
// ---------------------------------------------------------------------------
__global__ __launch_bounds__(256) void stage1_kernel(
    const float* __restrict__ rel,
    const ushort_t* __restrict__ w1F, const ushort_t* __restrict__ w2F,
    const float* __restrict__ b1, const float* __restrict__ b2,
    float* __restrict__ p1, float* __restrict__ p2)
{
    __shared__ __align__(16) char ldsA[16 * RD * 2];   // 16 KB
    int blk = blockIdx.x;
    int mt = blk >> 1, which = blk & 1;
    const ushort_t* wF = which ? w2F : w1F;
    const float* bias  = which ? b2 : b1;
    float* out         = which ? p2 : p1;
    int tid = threadIdx.x, wid = tid >> 6, lane = tid & 63;
    int lr = lane & 15, lg = lane >> 4;

#pragma unroll
    for (int it = 0; it < 8; ++it) {
        int rr = it * 2 + (tid >> 7);
        int c  = (tid & 127) * 4;
        float4 v = *reinterpret_cast<const float4*>(rel + (size_t)(mt * 16 + rr) * RD + c);
        short4 s;
        s.x = f2bf_fast(v.x); s.y = f2bf_fast(v.y);
        s.z = f2bf_fast(v.z); s.w = f2bf_fast(v.w);
        *reinterpret_cast<short4*>(ldsA + rr * (RD * 2) + ((c * 2) ^ ((rr & 7) << 4))) = s;
    }
    __syncthreads();

    int n0 = wid * 64;
    f32x4 acc[4] = {};
#pragma unroll
    for (int ks = 0; ks < 16; ++ks) {
        bf16x8 a = *reinterpret_cast<const bf16x8*>(
            ldsA + lr * (RD * 2) + ((ks * 64 + lg * 16) ^ ((lr & 7) << 4)));
#pragma unroll
        for (int nt = 0; nt < 4; ++nt) {
            int ntG = (n0 >> 4) + nt;
            bf16x8 bfr = *reinterpret_cast<const bf16x8*>(
                wF + ((size_t)(ntG * 16 + ks) * 64 + lane) * 8);
            acc[nt] = __builtin_amdgcn_mfma_f32_16x16x32_bf16(a, bfr, acc[nt], 0, 0, 0);
        }
    }
#pragma unroll
    for (int nt = 0; nt < 4; ++nt) {
        int col = n0 + nt * 16 + lr;
        float bv = bias[col];
#pragma unroll
        for (int r = 0; r < 4; ++r) {
            int orow = mt * 16 + lg * 4 + r;
            out[(size_t)orow * MD + col] = acc[nt][r] + bv;
        }
    }
}

// ---------------------------------------------------------------------------
// stage2: one block per (b,s,o1), transposed GEMM h^T = We^T * prod^T.
// XCD swizzle for group L2 locality. Epilogue: LN apply -> ALL THREE 16-row
// chunks staged in a 48KB LDS buffer -> ONE barrier -> one uninterrupted
// 48KB burst of wave-contiguous 1KB stores. Staging loads issued before
// afrag loads (staging feeds the first barrier; afrag needed only after).
// ---------------------------------------------------------------------------
__global__ __launch_bounds__(512, 4) void stage2_kernel(
    const float* __restrict__ p1, const float* __restrict__ p2,
    const ushort_t* __restrict__ weF,
    const float* __restrict__ be, const float* __restrict__ gamma,
    const float* __restrict__ beta, float* __restrict__ out)
{
    __shared__ __align__(16) char lds[49152];   // prod tile (24.5K) / epilogue (48K)
    __shared__ float pS1[NO][8];
    __shared__ float pS2[NO][8];
    __shared__ float muS[NO];
    __shared__ float rsS[NO];

    int d    = blockIdx.x;
    int bid  = (d & 7) * 576 + (d >> 3);   // 4608 = 8*576, bijective
    int grp  = (bid / NO) * NO;
    int tid  = threadIdx.x;
    int wid  = tid >> 6;
    int lane = tid & 63;
    int lr   = lane & 15;
    int lg   = lane >> 4;
    int m0w  = wid * 32;              // wave's n-row base

    // ---- stage prod rows into LDS (coalesced 1KB reads, swizzled writes) ----
    const float* p1r = p1 + (size_t)bid * MD;
#pragma unroll
    for (int i = 0; i < 6; ++i) {
        int r  = i * 8 + wid;
        int m0 = lane * 4;
        float4 x = *reinterpret_cast<const float4*>(p1r + m0);
        float4 y = *reinterpret_cast<const float4*>(p2 + (size_t)(grp + r) * MD + m0);
        short4 s;
        s.x = f2bf_fast(x.x * y.x); s.y = f2bf_fast(x.y * y.y);
        s.z = f2bf_fast(x.z * y.z); s.w = f2bf_fast(x.w * y.w);
        *reinterpret_cast<short4*>(lds + r * (MD * 2) + ((m0 * 2) ^ ((r & 7) << 4))) = s;
    }

    // ---- A fragments (weF): 16 coalesced 1KB loads (needed after barrier) ----
    bf16x8 afrag[2][8];
#pragma unroll
    for (int mt = 0; mt < 2; ++mt) {
        int ntG = (m0w >> 4) + mt;
#pragma unroll
        for (int ks = 0; ks < 8; ++ks)
            afrag[mt][ks] = *reinterpret_cast<const bf16x8*>(
                weF + ((size_t)(ntG * 8 + ks) * 64 + lane) * 8);
    }
    __syncthreads();

    // ---- K-loop: A from regs, B from LDS ----
    f32x4 acc[2][3] = {};
#pragma unroll
    for (int ks = 0; ks < 8; ++ks) {
        bf16x8 b[3];
#pragma unroll
        for (int nt = 0; nt < 3; ++nt) {
            int r = nt * 16 + lr;
            b[nt] = *reinterpret_cast<const bf16x8*>(
                lds + r * (MD * 2) + ((ks * 64 + lg * 16) ^ ((r & 7) << 4)));
        }
#pragma unroll
        for (int mt = 0; mt < 2; ++mt)
#pragma unroll
            for (int nt = 0; nt < 3; ++nt)
                acc[mt][nt] = __builtin_amdgcn_mfma_f32_16x16x32_bf16(
                    afrag[mt][ks], b[nt], acc[mt][nt], 0, 0, 0);
    }

    // ---- add be (per-n = per output row of h^T) ----
#pragma unroll
    for (int mt = 0; mt < 2; ++mt) {
        float4 bev = *reinterpret_cast<const float4*>(be + m0w + mt * 16 + lg * 4);
#pragma unroll
        for (int nt = 0; nt < 3; ++nt) {
            acc[mt][nt][0] += bev.x; acc[mt][nt][1] += bev.y;
            acc[mt][nt][2] += bev.z; acc[mt][nt][3] += bev.w;
        }
    }

    // ---- LN partials: per col r, lane-local 8-sum + xor16 + xor32 ----
#pragma unroll
    for (int nt = 0; nt < 3; ++nt) {
        float s1 = 0.f, s2 = 0.f;
#pragma unroll
        for (int mt = 0; mt < 2; ++mt)
#pragma unroll
            for (int r = 0; r < 4; ++r) {
                float v = acc[mt][nt][r];
                s1 += v; s2 += v * v;
            }
        s1 += __shfl_xor(s1, 16); s2 += __shfl_xor(s2, 16);
        s1 += __shfl_xor(s1, 32); s2 += __shfl_xor(s2, 32);
        if (lane < 16) {
            pS1[nt * 16 + lane][wid] = s1;
            pS2[nt * 16 + lane][wid] = s2;
        }
    }
    __syncthreads();   // pS ready; also fences last K-loop lds reads

    // ---- finalize stats: one thread per col ----
    if (tid < NO) {
        f32x4 a0 = *reinterpret_cast<const f32x4*>(&pS1[tid][0]);
        f32x4 a1 = *reinterpret_cast<const f32x4*>(&pS1[tid][4]);
        f32x4 b0 = *reinterpret_cast<const f32x4*>(&pS2[tid][0]);
        f32x4 b1v = *reinterpret_cast<const f32x4*>(&pS2[tid][4]);
        float S1 = a0[0]+a0[1]+a0[2]+a0[3] + a1[0]+a1[1]+a1[2]+a1[3];
        float S2 = b0[0]+b0[1]+b0[2]+b0[3] + b1v[0]+b1v[1]+b1v[2]+b1v[3];
        float m  = S1 * (1.0f / MD);
        float var = S2 * (1.0f / MD) - m * m;
        muS[tid] = m;
        rsS[tid] = rsqrtf(var + LN_EPS);
    }
    __syncthreads();

    // ---- epilogue: LN apply -> stage all 3 chunks (48KB) -> ONE barrier ->
    //      one contiguous 48KB store burst (wave-contiguous 1KB per instr).
    //      gamma/beta are per-FEATURE = per-n (float4 along n).
    float4 g4[2], b4[2];
#pragma unroll
    for (int mt = 0; mt < 2; ++mt) {
        g4[mt] = *reinterpret_cast<const float4*>(gamma + m0w + mt * 16 + lg * 4);
        b4[mt] = *reinterpret_cast<const float4*>(beta  + m0w + mt * 16 + lg * 4);
    }
#pragma unroll
    for (int nt = 0; nt < 3; ++nt) {
        int r = nt * 16 + lr;
        float mu = muS[r];
        float rs = rsS[r];
#pragma unroll
        for (int mt = 0; mt < 2; ++mt) {
            float4 o;
            o.x = (acc[mt][nt][0] - mu) * rs * g4[mt].x + b4[mt].x;
            o.y = (acc[mt][nt][1] - mu) * rs * g4[mt].y + b4[mt].y;
            o.z = (acc[mt][nt][2] - mu) * rs * g4[mt].z + b4[mt].z;
            o.w = (acc[mt][nt][3] - mu) * rs * g4[mt].w + b4[mt].w;
            int n4 = (m0w + mt * 16 + lg * 4) * 4;           // byte offset of n
            *reinterpret_cast<float4*>(
                lds + nt * 16384 + lr * 1024 + (n4 ^ ((lr & 7) << 4))) = o;
        }
    }
    __syncthreads();   // all 48 rows staged

    size_t ob = (size_t)bid * NO * MD;
#pragma unroll
    for (int nt = 0; nt < 3; ++nt) {
#pragma unroll
        for (int j = 0; j < 2; ++j) {
            int rl = wid * 2 + j;     // 16 rows per chunk, 2 per wave
            float4 o = *reinterpret_cast<const float4*>(
                lds + nt * 16384 + rl * 1024 + ((lane * 16) ^ ((rl & 7) << 4)));
            *reinterpret_cast<float4*>(
                out + ob + (size_t)(nt * 16 + rl) * MD + lane * 4) = o;
        }
    }
}

// ---------------------------------------------------------------------------
extern "C" void kernel_launch(void* const* d_in, const int* in_sizes, int n_in,
                              void* d_out, int out_size, void* d_ws, size_t ws_size,
                              hipStream_t stream) {
    const float* rel   = (const float*)d_in[0];
    const float* W1    = (const float*)d_in[1];
    const float* b1    = (const float*)d_in[2];
    const float* W2    = (const float*)d_in[3];
    const float* b2    = (const float*)d_in[4];
    const float* We    = (const float*)d_in[5];
    const float* be    = (const float*)d_in[6];
    const float* gamma = (const float*)d_in[7];
    const float* beta  = (const float*)d_in[8];
    float* out = (float*)d_out;

    char* ws = (char*)d_ws;
    // ws layout (bytes): w1F 512K | w2F 512K | weF 128K | p1 4.5M | p2 4.5M
    ushort_t* w1F = (ushort_t*)(ws);
    ushort_t* w2F = (ushort_t*)(ws + 524288);
    ushort_t* weF = (ushort_t*)(ws + 1048576);
    float*    p1  = (float*)   (ws + 1179648);
    float*    p2  = (float*)   (ws + 1179648 + 4718592);

    prep_kernel<<<80, 512, 0, stream>>>(W1, W2, We, w1F, w2F, weF);
    stage1_kernel<<<576, 256, 0, stream>>>(rel, w1F, w2F, b1, b2, p1, p2);
    stage2_kernel<<<M1, 512, 0, stream>>>(p1, p2, weF, be, gamma, beta, out);
}